// Round 14
// baseline (1488.640 us; speedup 1.0000x reference)
//
#include <hip/hip_runtime.h>
#include <math.h>

#define DEVI __device__ __forceinline__

namespace {

constexpr int Bn   = 2048;
constexpr int En   = 6;
constexpr int Hn   = 4;
constexpr int Dn   = 128;
constexpr int DHn  = 32;
constexpr int LTn  = 24;   // text length
constexpr int CSn  = 20;   // chunk (decoder query) length
constexpr int JDn  = 7;
constexpr int SDn  = 16;
constexpr int NLBn = 4;
constexpr int NLDn = 3;
constexpr int DFFn = 512;
constexpr float INV_SQRT_DH = 0.17677669529663687f;  // 1/sqrt(32)

// expert phase-pipeline geometry
constexpr int PAIRS  = 4096;                  // 2048 items x top-2
constexpr int MPMAX  = PAIRS * 20 + En * 128; // padded rows (per-expert 128-aligned)
constexpr int NBGMAX = PAIRS * 20 / 128 + En; // 646 grouped-GEMM blocks max
constexpr int GEXP_OFF = 64;
constexpr int GMT_OFF  = 64 + NBGMAX;

// BERT pipeline geometry
constexpr int ROWSB = Bn * LTn;               // 49152 rows, 3072 M-tiles, no padding

// per-head attention LDS stride (36 mod 32 = 4 -> conflict-light, 16B-aligned)
constexpr int HSTR = 36;

typedef float f32x4v __attribute__((ext_vector_type(4)));
typedef short short8 __attribute__((ext_vector_type(8)));

DEVI float geluf(float x) { return 0.5f * x * (1.0f + erff(x * 0.70710678118654752f)); }

DEVI short f2bf(float f) {  // fp32 -> bf16 bits, round-to-nearest-even
  unsigned u = __float_as_uint(f);
  return (short)((u + 0x7FFFu + ((u >> 16) & 1u)) >> 16);
}
DEVI float bf2f(short s) { return __uint_as_float(((unsigned)(unsigned short)s) << 16); }
DEVI void split2(float v, short& h, short& l) {  // v ~= hi + lo to ~2^-16 rel
  h = f2bf(v);
  l = f2bf(v - bf2f(h));
}

// packed-A position for (row, col), K-tile count KT
DEVI size_t apos(int row, int col, int KT) {
  return (((size_t)(row >> 4) * KT + (col >> 5)) * 64 + ((col >> 3) & 3) * 16 + (row & 15)) * 8
         + (col & 7);
}

// local packed-H position (row local rl, col in [0,512), KT=16)
DEVI size_t hpos(int rl, int col) {
  return (((size_t)((rl >> 4) * 16 + (col >> 5)) * 64) + ((col >> 3) & 3) * 16 + (rl & 15)) * 8
         + (col & 7);
}

// ---------------------------------------------------------------------------
// pack fp32 [K][N] into single-bf16 B tiles (512 shorts/tile)
__global__ void pack_kernel(const float* __restrict__ W, short* __restrict__ out,
                            const int K, const int N, const int total)
{
  const int p = (int)blockIdx.x * 256 + (int)threadIdx.x;
  if (p >= total) return;
  const int perMat = (K * N) >> 3;
  const int m = p / perMat, r = p - m * perMat;
  const int t = r >> 6, lane = r & 63;
  const int KT = K >> 5;
  const int nt = t / KT, kt = t - nt * KT;
  const int row0 = kt * 32 + (lane >> 4) * 8;
  const int col  = nt * 16 + (lane & 15);
  const float* src = W + (size_t)m * K * N;
  short8 v;
#pragma unroll
  for (int j = 0; j < 8; ++j) v[j] = f2bf(src[(size_t)(row0 + j) * N + col]);
  *reinterpret_cast<short8*>(out + (size_t)p * 8) = v;
}

// pack fp32 [K][N] into split hi/lo B tiles (1024 shorts/tile)
__global__ void pack2_kernel(const float* __restrict__ W, short* __restrict__ out,
                             const int K, const int N, const int total)
{
  const int p = (int)blockIdx.x * 256 + (int)threadIdx.x;
  if (p >= total) return;
  const int perMat = (K * N) >> 3;
  const int m = p / perMat, r = p - m * perMat;
  const int t = r >> 6, lane = r & 63;
  const int KT = K >> 5;
  const int nt = t / KT, kt = t - nt * KT;
  const int row0 = kt * 32 + (lane >> 4) * 8;
  const int col  = nt * 16 + (lane & 15);
  const float* src = W + (size_t)m * K * N;
  short8 vh, vl;
#pragma unroll
  for (int j = 0; j < 8; ++j) {
    short hh, ll;
    split2(src[(size_t)(row0 + j) * N + col], hh, ll);
    vh[j] = hh; vl[j] = ll;
  }
  const size_t T  = (size_t)(perMat >> 6);
  const size_t tg = (size_t)m * T + t;
  *reinterpret_cast<short8*>(out + tg * 1024 + lane * 8)       = vh;
  *reinterpret_cast<short8*>(out + tg * 1024 + 512 + lane * 8) = vl;
}

// ===========================================================================
// BERT phase pipeline (split-bf16, M = 49152 rows)
// ===========================================================================

__global__ __launch_bounds__(256) void bembed_kernel(
    const int* __restrict__ ids, const float* __restrict__ tok,
    const float* __restrict__ pos, float* __restrict__ X,
    short* __restrict__ Ah, short* __restrict__ Al)
{
  const int mt = (int)blockIdx.x;          // 0..3071
  const int t = (int)threadIdx.x;
  const int rl = t >> 4, j = t & 15;
  const int row = mt * 16 + rl;
  const int b = row / 24, i = row - b * 24;
  const int id = ids[b * 24 + i];
  const float* tp = tok + (size_t)id * 128 + j * 8;
  const float* pp = pos + i * 128 + j * 8;
  float x[8];
  short8 vh, vl;
#pragma unroll
  for (int u = 0; u < 8; ++u) {
    x[u] = tp[u] + pp[u];
    short hh, ll; split2(x[u], hh, ll);
    vh[u] = hh; vl[u] = ll;
  }
  float4 f0 = {x[0], x[1], x[2], x[3]}, f1 = {x[4], x[5], x[6], x[7]};
  *reinterpret_cast<float4*>(X + (size_t)row * 128 + j * 8) = f0;
  *reinterpret_cast<float4*>(X + (size_t)row * 128 + j * 8 + 4) = f1;
  const size_t pk = (((size_t)mt * 4 + (j >> 2)) * 64 + (j & 3) * 16 + rl) * 8;
  *reinterpret_cast<short8*>(Ah + pk) = vh;
  *reinterpret_cast<short8*>(Al + pk) = vl;
}

__global__ __launch_bounds__(256) void bqkv_kernel(
    const short* __restrict__ Ah, const short* __restrict__ Al,
    const short* __restrict__ Bp, const float* __restrict__ bias,
    float* __restrict__ Out)
{
  const int mt0 = (int)blockIdx.x * 4;
  const int nc  = (int)blockIdx.y;
  const int lane = (int)threadIdx.x & 63, wv = (int)threadIdx.x >> 6;
  const int r0 = lane & 15, g = lane >> 4;
  short8 bh[2][4], bl[2][4];
#pragma unroll
  for (int i = 0; i < 2; ++i)
#pragma unroll
    for (int kt = 0; kt < 4; ++kt) {
      const short* tb = Bp + (((size_t)(nc * 8 + wv * 2 + i) * 4 + kt) << 10);
      bh[i][kt] = *reinterpret_cast<const short8*>(tb + lane * 8);
      bl[i][kt] = *reinterpret_cast<const short8*>(tb + 512 + lane * 8);
    }
#pragma unroll 2
  for (int mt = 0; mt < 4; ++mt) {
    const int mtg = mt0 + mt;
    short8 ah[4], al[4];
#pragma unroll
    for (int kt = 0; kt < 4; ++kt) {
      ah[kt] = *reinterpret_cast<const short8*>(Ah + (((size_t)mtg * 4 + kt) * 64 + lane) * 8);
      al[kt] = *reinterpret_cast<const short8*>(Al + (((size_t)mtg * 4 + kt) * 64 + lane) * 8);
    }
#pragma unroll
    for (int i = 0; i < 2; ++i) {
      f32x4v c = {0.f, 0.f, 0.f, 0.f};
#pragma unroll
      for (int kt = 0; kt < 4; ++kt) {
        c = __builtin_amdgcn_mfma_f32_16x16x32_bf16(ah[kt], bh[i][kt], c, 0, 0, 0);
        c = __builtin_amdgcn_mfma_f32_16x16x32_bf16(al[kt], bh[i][kt], c, 0, 0, 0);
        c = __builtin_amdgcn_mfma_f32_16x16x32_bf16(ah[kt], bl[i][kt], c, 0, 0, 0);
      }
      const int col = nc * 128 + (wv * 2 + i) * 16 + r0;
      const float bb = bias[col];
#pragma unroll
      for (int q = 0; q < 4; ++q)
        Out[(size_t)(mtg * 16 + g * 4 + q) * 384 + col] = c[q] + bb;
    }
  }
}

// per (item, head) BERT attention: QKV fp32 -> attn out split-packed A.
// grid (2048, 4), 64 threads. Wave-parallel softmax, norm folded into AV.
__global__ __launch_bounds__(64) void battn_kernel(
    const float* __restrict__ QKV, const int* __restrict__ ids,
    short* __restrict__ Ah, short* __restrict__ Al)
{
  __shared__ float qs[LTn * HSTR], ks[LTn * HSTR], vs[LTn * HSTR];
  __shared__ float att[LTn * LTn];
  __shared__ float inv[LTn];
  __shared__ int pad_s[LTn];
  const int b = (int)blockIdx.x, h = (int)blockIdx.y;
  const int tid = (int)threadIdx.x;
  const int row0 = b * LTn;
  for (int u = tid; u < LTn * 24; u += 64) {
    const int il = u / 24, r = u % 24, which = r >> 3, d4 = r & 7;
    const float4 v = *reinterpret_cast<const float4*>(
        QKV + (size_t)(row0 + il) * 384 + which * 128 + h * 32 + d4 * 4);
    float* dst = (which == 0 ? qs : which == 1 ? ks : vs) + il * HSTR + d4 * 4;
    *reinterpret_cast<float4*>(dst) = v;
  }
  if (tid < LTn) pad_s[tid] = (ids[row0 + tid] == 0) ? 1 : 0;
  __syncthreads();
  for (int e = tid; e < LTn * LTn; e += 64) {
    const int i = e / LTn, j = e % LTn;
    const float* qp = qs + i * HSTR;
    const float* kp = ks + j * HSTR;
    float acc = 0.f;
#pragma unroll
    for (int d = 0; d < DHn; d += 4) {
      const float4 qa = *reinterpret_cast<const float4*>(qp + d);
      const float4 kb = *reinterpret_cast<const float4*>(kp + d);
      acc += qa.x * kb.x + qa.y * kb.y + qa.z * kb.z + qa.w * kb.w;
    }
    acc *= INV_SQRT_DH;
    if (pad_s[j]) acc = -1e9f;
    att[e] = acc;
  }
  __syncthreads();
  if (tid < 2 * LTn) {                 // 48 lanes: 2 per row, 12 elems each
    const int r = tid >> 1, h0 = (tid & 1) * 12;
    float* row = att + r * LTn + h0;
    float m = row[0];
#pragma unroll
    for (int j = 1; j < 12; ++j) m = fmaxf(m, row[j]);
    m = fmaxf(m, __shfl_xor(m, 1));
    float s = 0.f;
#pragma unroll
    for (int j = 0; j < 12; ++j) { const float ex = expf(row[j] - m); row[j] = ex; s += ex; }
    s += __shfl_xor(s, 1);
    if ((tid & 1) == 0) inv[r] = 1.f / s;
  }
  __syncthreads();
  for (int e = tid; e < LTn * 32; e += 64) {
    const int i = e >> 5, c = e & 31;
    const float* arow = att + i * LTn;
    float acc = 0.f;
#pragma unroll 4
    for (int j = 0; j < LTn; ++j) acc = fmaf(arow[j], vs[j * HSTR + c], acc);
    acc *= inv[i];
    short hh, ll; split2(acc, hh, ll);
    const size_t pk = apos(row0 + i, h * 32 + c, 4);
    Ah[pk] = hh; Al[pk] = ll;
  }
}

__global__ __launch_bounds__(256) void bo_ln_kernel(
    const short* __restrict__ Ah, const short* __restrict__ Al,
    const short* __restrict__ Bp, const float* __restrict__ bo,
    const float* __restrict__ gs, const float* __restrict__ gb,
    float* __restrict__ X, short* __restrict__ OAh, short* __restrict__ OAl)
{
  __shared__ float red[16][4][2];
  const int mt0 = (int)blockIdx.x * 4;
  const int lane = (int)threadIdx.x & 63, wv = (int)threadIdx.x >> 6;
  const int r0 = lane & 15, g = lane >> 4;
  short8 bh[2][4], bl[2][4];
#pragma unroll
  for (int i = 0; i < 2; ++i)
#pragma unroll
    for (int kt = 0; kt < 4; ++kt) {
      const short* tb = Bp + (((size_t)(wv * 2 + i) * 4 + kt) << 10);
      bh[i][kt] = *reinterpret_cast<const short8*>(tb + lane * 8);
      bl[i][kt] = *reinterpret_cast<const short8*>(tb + 512 + lane * 8);
    }
  for (int mt = 0; mt < 4; ++mt) {
    const int mtg = mt0 + mt;
    short8 ah[4], al[4];
#pragma unroll
    for (int kt = 0; kt < 4; ++kt) {
      ah[kt] = *reinterpret_cast<const short8*>(Ah + (((size_t)mtg * 4 + kt) * 64 + lane) * 8);
      al[kt] = *reinterpret_cast<const short8*>(Al + (((size_t)mtg * 4 + kt) * 64 + lane) * 8);
    }
    float v[2][4];
#pragma unroll
    for (int i = 0; i < 2; ++i) {
      f32x4v c = {0.f, 0.f, 0.f, 0.f};
#pragma unroll
      for (int kt = 0; kt < 4; ++kt) {
        c = __builtin_amdgcn_mfma_f32_16x16x32_bf16(ah[kt], bh[i][kt], c, 0, 0, 0);
        c = __builtin_amdgcn_mfma_f32_16x16x32_bf16(al[kt], bh[i][kt], c, 0, 0, 0);
        c = __builtin_amdgcn_mfma_f32_16x16x32_bf16(ah[kt], bl[i][kt], c, 0, 0, 0);
      }
      const int col = (wv * 2 + i) * 16 + r0;
      const float bb = bo[col];
#pragma unroll
      for (int q = 0; q < 4; ++q) {
        const int row = mtg * 16 + g * 4 + q;
        v[i][q] = c[q] + bb + X[(size_t)row * 128 + col];
      }
    }
    float s1[4], s2[4];
#pragma unroll
    for (int q = 0; q < 4; ++q) {
      s1[q] = v[0][q] + v[1][q];
      s2[q] = v[0][q] * v[0][q] + v[1][q] * v[1][q];
    }
#pragma unroll
    for (int o = 1; o < 16; o <<= 1)
#pragma unroll
      for (int q = 0; q < 4; ++q) { s1[q] += __shfl_xor(s1[q], o); s2[q] += __shfl_xor(s2[q], o); }
    if (r0 == 0)
#pragma unroll
      for (int q = 0; q < 4; ++q) { red[g * 4 + q][wv][0] = s1[q]; red[g * 4 + q][wv][1] = s2[q]; }
    __syncthreads();
#pragma unroll
    for (int q = 0; q < 4; ++q) {
      const int r = g * 4 + q;
      const float t1 = red[r][0][0] + red[r][1][0] + red[r][2][0] + red[r][3][0];
      const float t2 = red[r][0][1] + red[r][1][1] + red[r][2][1] + red[r][3][1];
      const float m  = t1 * (1.f / 128.f);
      const float rs = rsqrtf(t2 * (1.f / 128.f) - m * m + 1e-5f);
      const int row = mtg * 16 + r;
#pragma unroll
      for (int i = 0; i < 2; ++i) {
        const int col = (wv * 2 + i) * 16 + r0;
        const float o = (v[i][q] - m) * rs * gs[col] + gb[col];
        X[(size_t)row * 128 + col] = o;   // post-LN: LN'd value IS the residual
        short hh, ll; split2(o, hh, ll);
        const size_t pk = apos(row, col, 4);
        OAh[pk] = hh; OAl[pk] = ll;
      }
    }
    __syncthreads();
  }
}

// fused BERT FFN: H = gelu(A@W1+b1) kept in LDS; X = LN(X + H@W2 + b2); pack A.
// 512 threads (8 waves), 32 rows/block, grid ROWSB/32 = 1536.
// B-tile loads double-buffered (1-deep) in both phases; MFMA order unchanged.
#define BFFN_LOADW1(ii, BH, BL)                                             \
  {                                                                         \
    const int nt_ = wv * 4 + (ii);                                          \
    for (int kt = 0; kt < 4; ++kt) {                                        \
      const short* tb_ = W1p + (((size_t)(nt_ * 4 + kt)) << 10);            \
      BH[kt] = *reinterpret_cast<const short8*>(tb_ + lane * 8);            \
      BL[kt] = *reinterpret_cast<const short8*>(tb_ + 512 + lane * 8);      \
    }                                                                       \
  }
#define BFFN_COMP1(ii, BH, BL)                                              \
  {                                                                         \
    const int nt_ = wv * 4 + (ii);                                          \
    const int col_ = nt_ * 16 + r0;                                         \
    const float bb_ = b1[col_];                                             \
    for (int mtl = 0; mtl < 2; ++mtl) {                                     \
      f32x4v c = {0.f, 0.f, 0.f, 0.f};                                      \
      for (int kt = 0; kt < 4; ++kt) {                                      \
        c = __builtin_amdgcn_mfma_f32_16x16x32_bf16(ah[mtl][kt], BH[kt], c, 0, 0, 0); \
        c = __builtin_amdgcn_mfma_f32_16x16x32_bf16(al[mtl][kt], BH[kt], c, 0, 0, 0); \
        c = __builtin_amdgcn_mfma_f32_16x16x32_bf16(ah[mtl][kt], BL[kt], c, 0, 0, 0); \
      }                                                                     \
      for (int q = 0; q < 4; ++q) {                                         \
        const int rl_ = mtl * 16 + g * 4 + q;                               \
        short hh_, ll_; split2(geluf(c[q] + bb_), hh_, ll_);                \
        const size_t hp_ = hpos(rl_, col_);                                 \
        HhL[hp_] = hh_; HlL[hp_] = ll_;                                     \
      }                                                                     \
    }                                                                       \
  }
#define BFFN_LOADW2(kk, DH, DL)                                             \
  {                                                                         \
    const short* tb_ = W2p + (((size_t)(wv * 16 + (kk))) << 10);            \
    DH = *reinterpret_cast<const short8*>(tb_ + lane * 8);                  \
    DL = *reinterpret_cast<const short8*>(tb_ + 512 + lane * 8);            \
  }
#define BFFN_COMP2(kk, DH, DL)                                              \
  {                                                                         \
    for (int mtl = 0; mtl < 2; ++mtl) {                                     \
      const size_t ap_ = (((size_t)(mtl * 16 + (kk)) * 64 + lane)) * 8;     \
      const short8 a2h_ = *reinterpret_cast<const short8*>(HhL + ap_);      \
      const short8 a2l_ = *reinterpret_cast<const short8*>(HlL + ap_);      \
      c2[mtl] = __builtin_amdgcn_mfma_f32_16x16x32_bf16(a2h_, DH, c2[mtl], 0, 0, 0); \
      c2[mtl] = __builtin_amdgcn_mfma_f32_16x16x32_bf16(a2l_, DH, c2[mtl], 0, 0, 0); \
      c2[mtl] = __builtin_amdgcn_mfma_f32_16x16x32_bf16(a2h_, DL, c2[mtl], 0, 0, 0); \
    }                                                                       \
  }

__global__ __launch_bounds__(512) void bffn_kernel(
    const short* __restrict__ Ah, const short* __restrict__ Al,
    const short* __restrict__ W1p, const short* __restrict__ W2p,
    const float* __restrict__ b1, const float* __restrict__ b2,
    const float* __restrict__ gs, const float* __restrict__ gb,
    float* __restrict__ X, short* __restrict__ OAh, short* __restrict__ OAl)
{
  __shared__ short HhL[2 * 16 * 64 * 8];   // 32 KB
  __shared__ short HlL[2 * 16 * 64 * 8];   // 32 KB
  __shared__ float red[16][8][2];
  const int mtg0 = (int)blockIdx.x * 2;
  const int lane = (int)threadIdx.x & 63, wv = (int)threadIdx.x >> 6;  // 8 waves
  const int r0 = lane & 15, g = lane >> 4;
  // persistent A fragments (2 local M-tiles)
  short8 ah[2][4], al[2][4];
#pragma unroll
  for (int mtl = 0; mtl < 2; ++mtl)
#pragma unroll
    for (int kt = 0; kt < 4; ++kt) {
      ah[mtl][kt] = *reinterpret_cast<const short8*>(
          Ah + (((size_t)(mtg0 + mtl) * 4 + kt) * 64 + lane) * 8);
      al[mtl][kt] = *reinterpret_cast<const short8*>(
          Al + (((size_t)(mtg0 + mtl) * 4 + kt) * 64 + lane) * 8);
    }
  // phase 1: W1 + gelu -> LDS (split), double-buffered W1 tiles
  {
    short8 bhA[4], blA[4], bhB[4], blB[4];
    BFFN_LOADW1(0, bhA, blA)
    BFFN_LOADW1(1, bhB, blB)
    BFFN_COMP1(0, bhA, blA)
    BFFN_LOADW1(2, bhA, blA)
    BFFN_COMP1(1, bhB, blB)
    BFFN_LOADW1(3, bhB, blB)
    BFFN_COMP1(2, bhA, blA)
    BFFN_COMP1(3, bhB, blB)
  }
  __syncthreads();
  // phase 2: H@W2 (K=512 from LDS) + residual + LN + pack; W2 double-buffered
  const int col = wv * 16 + r0;
  f32x4v c2[2];
#pragma unroll
  for (int mtl = 0; mtl < 2; ++mtl) c2[mtl] = (f32x4v){0.f, 0.f, 0.f, 0.f};
  {
    short8 w2hA, w2lA, w2hB, w2lB;
    BFFN_LOADW2(0, w2hA, w2lA)
    BFFN_LOADW2(1, w2hB, w2lB)
#pragma unroll
    for (int kk = 0; kk < 16; kk += 2) {
      BFFN_COMP2(kk, w2hA, w2lA)
      if (kk + 2 < 16) BFFN_LOADW2(kk + 2, w2hA, w2lA)
      BFFN_COMP2(kk + 1, w2hB, w2lB)
      if (kk + 3 < 16) BFFN_LOADW2(kk + 3, w2hB, w2lB)
    }
  }
  const float bb2 = b2[col];
  for (int mtl = 0; mtl < 2; ++mtl) {
    const int mtg = mtg0 + mtl;
    float v[4], s1[4], s2[4];
#pragma unroll
    for (int q = 0; q < 4; ++q) {
      const int row = mtg * 16 + g * 4 + q;
      v[q] = c2[mtl][q] + bb2 + X[(size_t)row * 128 + col];
      s1[q] = v[q]; s2[q] = v[q] * v[q];
    }
#pragma unroll
    for (int o = 1; o < 16; o <<= 1)
#pragma unroll
      for (int q = 0; q < 4; ++q) { s1[q] += __shfl_xor(s1[q], o); s2[q] += __shfl_xor(s2[q], o); }
    if (r0 == 0)
#pragma unroll
      for (int q = 0; q < 4; ++q) { red[g * 4 + q][wv][0] = s1[q]; red[g * 4 + q][wv][1] = s2[q]; }
    __syncthreads();
#pragma unroll
    for (int q = 0; q < 4; ++q) {
      const int r = g * 4 + q;
      float t1 = 0.f, t2 = 0.f;
#pragma unroll
      for (int w = 0; w < 8; ++w) { t1 += red[r][w][0]; t2 += red[r][w][1]; }
      const float m  = t1 * (1.f / 128.f);
      const float rs = rsqrtf(t2 * (1.f / 128.f) - m * m + 1e-5f);
      const int row = mtg * 16 + r;
      const float o = (v[q] - m) * rs * gs[col] + gb[col];
      X[(size_t)row * 128 + col] = o;     // post-LN
      short hh, ll; split2(o, hh, ll);
      const size_t pk = apos(row, col, 4);
      OAh[pk] = hh; OAl[pk] = ll;
    }
    __syncthreads();
  }
}

__global__ __launch_bounds__(256) void bintent_kernel(
    const float* __restrict__ X, const float* __restrict__ lnf_s,
    const float* __restrict__ lnf_b, float* __restrict__ intent)
{
  const int w = (int)threadIdx.x >> 6, lane = (int)threadIdx.x & 63;
  const int b = (int)blockIdx.x * 4 + w;
  const float* xr = X + (size_t)b * LTn * 128;
  const float a0 = xr[lane], a1 = xr[lane + 64];
  float s1 = a0 + a1, s2 = a0 * a0 + a1 * a1;
#pragma unroll
  for (int o = 32; o > 0; o >>= 1) { s1 += __shfl_xor(s1, o); s2 += __shfl_xor(s2, o); }
  const float m  = s1 * (1.f / 128.f);
  const float rs = rsqrtf(s2 * (1.f / 128.f) - m * m + 1e-5f);
  intent[b * 128 + lane]      = (a0 - m) * rs * lnf_s[lane]      + lnf_b[lane];
  intent[b * 128 + lane + 64] = (a1 - m) * rs * lnf_s[lane + 64] + lnf_b[lane + 64];
}

// ---------------------------------------------------------------------------
struct RouterP {
  const float* state; const float* intent;
  const float* se_W1; const float* se_b1; const float* se_W2; const float* se_b2;
  const float* se_ln_s; const float* se_ln_b;
  const float* r_W1; const float* r_b1; const float* r_W2; const float* r_b2;
  const float* r_ln_s; const float* r_ln_b;
  const float* gate_W; const float* gate_b;
  int* ridx; float* rwgt;
};

DEVI void ln128(float* x, const float* gs, const float* gb, float* red)
{
  const int c = (int)threadIdx.x;      // blockDim == 128
  const float a = x[c];
  float s1 = a, s2 = a * a;
#pragma unroll
  for (int o = 32; o > 0; o >>= 1) { s1 += __shfl_xor(s1, o); s2 += __shfl_xor(s2, o); }
  const int wid = c >> 6;
  if ((c & 63) == 0) { red[wid * 2] = s1; red[wid * 2 + 1] = s2; }
  __syncthreads();
  s1 = red[0] + red[2]; s2 = red[1] + red[3];
  const float m  = s1 * (1.f / 128.f);
  const float rs = rsqrtf(s2 * (1.f / 128.f) - m * m + 1e-5f);
  __syncthreads();
  x[c] = (a - m) * rs * gs[c] + gb[c];
}

// 128-deep dot with 4 independent accumulator chains (latency fix)
DEVI float dot128i(const float* __restrict__ h, const float* __restrict__ W,
                   const int c, const int wstr)
{
  float a0 = 0.f, a1 = 0.f, a2 = 0.f, a3 = 0.f;
#pragma unroll 8
  for (int k = 0; k < 128; k += 4) {
    a0 = fmaf(h[k + 0], W[(k + 0) * wstr + c], a0);
    a1 = fmaf(h[k + 1], W[(k + 1) * wstr + c], a1);
    a2 = fmaf(h[k + 2], W[(k + 2) * wstr + c], a2);
    a3 = fmaf(h[k + 3], W[(k + 3) * wstr + c], a3);
  }
  return (a0 + a1) + (a2 + a3);
}

__global__ __launch_bounds__(128) void router_kernel(RouterP p)
{
  __shared__ float sstate[SDn];
  __shared__ float h1[Dn];
  __shared__ float vv[Dn];
  __shared__ float red[4];
  __shared__ float slog[En];
  const int b = blockIdx.x;
  const int c = (int)threadIdx.x;

  if (c < SDn) sstate[c] = p.state[b * SDn + c];
  __syncthreads();
  {
    float acc = p.se_b1[c];
#pragma unroll
    for (int k = 0; k < SDn; ++k) acc = fmaf(sstate[k], p.se_W1[k * Dn + c], acc);
    h1[c] = geluf(acc);
  }
  __syncthreads();
  vv[c] = p.se_b2[c] + dot128i(h1, p.se_W2, c, Dn);
  __syncthreads();
  ln128(vv, p.se_ln_s, p.se_ln_b, red);
  __syncthreads();
  {
    const float* ib = p.intent + b * Dn;
    float acc = p.r_b1[c] + dot128i(ib, p.r_W1, c, Dn)
                          + dot128i(vv, p.r_W1 + Dn * Dn, c, Dn);
    h1[c] = geluf(acc);
  }
  __syncthreads();
  vv[c] = p.r_b2[c] + dot128i(h1, p.r_W2, c, Dn);
  __syncthreads();
  ln128(vv, p.r_ln_s, p.r_ln_b, red);
  __syncthreads();
  if (c < En) slog[c] = p.gate_b[c] + dot128i(vv, p.gate_W, c, En);
  __syncthreads();
  if (c == 0) {
    int i0 = 0; float v0 = slog[0];
#pragma unroll
    for (int e2 = 1; e2 < En; ++e2) if (slog[e2] > v0) { v0 = slog[e2]; i0 = e2; }
    int i1 = -1; float v1 = -3.4e38f;
#pragma unroll
    for (int e2 = 0; e2 < En; ++e2) if (e2 != i0 && slog[e2] > v1) { v1 = slog[e2]; i1 = e2; }
    const float e1  = expf(v1 - v0);
    const float inv = 1.f / (1.f + e1);
    p.ridx[b * 2 + 0] = i0; p.ridx[b * 2 + 1] = i1;
    p.rwgt[b * 2 + 0] = inv; p.rwgt[b * 2 + 1] = e1 * inv;
  }
}

// ===========================================================================
// EXPERT PHASE PIPELINE — norm_first: X keeps RAW residual, packed A gets LN
// ===========================================================================

__global__ void sched_kernel(const int* __restrict__ ridx, int* __restrict__ sch,
                             int* plist, int* prow, int* pexp, int* ppos)
{
  __shared__ int scnt[En], scur[En], soff[En], srb[En + 1];
  const int t = (int)threadIdx.x;
  if (t < En) { scnt[t] = 0; scur[t] = 0; }
  __syncthreads();
  for (int p = t; p < PAIRS; p += 256) atomicAdd(&scnt[ridx[p]], 1);
  __syncthreads();
  if (t == 0) {
    int off = 0, rb = 0, k = 0;
    for (int e = 0; e < En; ++e) {
      soff[e] = off; srb[e] = rb;
      const int rows = scnt[e] * 20;
      const int nb = (rows + 127) >> 7;
      for (int q = 0; q < nb; ++q) {
        sch[GEXP_OFF + k] = e;
        sch[GMT_OFF + k]  = (rb >> 4) + q * 8;
        ++k;
      }
      off += scnt[e];
      rb += nb * 128;
    }
    srb[En] = rb;
    sch[0] = k;
    for (int e = 0; e < En; ++e) { sch[1 + e] = scnt[e]; sch[7 + e] = soff[e]; }
    for (int e = 0; e <= En; ++e) sch[13 + e] = srb[e];
  }
  __syncthreads();
  for (int p = t; p < PAIRS; p += 256) {
    const int e = ridx[p];
    const int pos = atomicAdd(&scur[e], 1);
    const int i = soff[e] + pos;
    plist[i] = p; ppos[p] = i; pexp[i] = e; prow[i] = srb[e] + pos * 20;
  }
}

__global__ void xinit_kernel(const float* __restrict__ qpe, const int* __restrict__ sch,
                             float* __restrict__ X)
{
  const int idx = (int)blockIdx.x * 256 + (int)threadIdx.x;  // quad index
  const int row = idx >> 5;
  if (row >= MPMAX) return;
  const int c4 = (idx & 31) * 4;
  const int* RB = sch + 13;
  float4 v = {0.f, 0.f, 0.f, 0.f};
  int e = 0;
  while (e < En && row >= RB[e + 1]) ++e;
  if (e < En) {
    const int local = row - RB[e];
    if (local < sch[1 + e] * 20) {
      const int r = local - (local / 20) * 20;
      v = *reinterpret_cast<const float4*>(qpe + r * 128 + c4);
    }
  }
  *reinterpret_cast<float4*>(X + (size_t)row * 128 + c4) = v;
}

// LN over X rows -> packed bf16 A-fragments (used once, layer-0 sub-0)
__global__ __launch_bounds__(256) void ln_pack_kernel(
    const float* __restrict__ X, short* __restrict__ XnP,
    const float* __restrict__ lns_all, const float* __restrict__ lnb_all,
    const int subOff, const int* __restrict__ sch)
{
  const int* RB = sch + 13;
  const int mt = (int)blockIdx.x;
  const int row0 = mt << 4;
  if (row0 >= RB[En]) return;
  int e = 0;
  while (e < En - 1 && row0 >= RB[e + 1]) ++e;
  const float* gs = lns_all + e * (NLDn * 3 * 128) + subOff;
  const float* gb = lnb_all + e * (NLDn * 3 * 128) + subOff;
  const int t = (int)threadIdx.x;
  const int rl = t >> 4, j = t & 15;
  const int row = row0 + rl;
  float x[8];
  {
    const float4 a = *reinterpret_cast<const float4*>(X + (size_t)row * 128 + j * 8);
    const float4 bq = *reinterpret_cast<const float4*>(X + (size_t)row * 128 + j * 8 + 4);
    x[0] = a.x; x[1] = a.y; x[2] = a.z; x[3] = a.w;
    x[4] = bq.x; x[5] = bq.y; x[6] = bq.z; x[7] = bq.w;
  }
  float s1 = 0.f, s2 = 0.f;
#pragma unroll
  for (int u = 0; u < 8; ++u) { s1 += x[u]; s2 += x[u] * x[u]; }
#pragma unroll
  for (int o = 1; o < 16; o <<= 1) { s1 += __shfl_xor(s1, o); s2 += __shfl_xor(s2, o); }
  const float m  = s1 * (1.f / 128.f);
  const float rs = rsqrtf(s2 * (1.f / 128.f) - m * m + 1e-5f);
  short8 pk;
#pragma unroll
  for (int u = 0; u < 8; ++u)
    pk[u] = f2bf((x[u] - m) * rs * gs[j * 8 + u] + gb[j * 8 + u]);
  const int kt = j >> 2, g = j & 3, lp = g * 16 + rl;
  *reinterpret_cast<short8*>(XnP + (((size_t)mt * 4 + kt) * 64 + lp) * 8) = pk;
}

// composite cross-attn K/V factors
__global__ __launch_bounds__(256) void compose_kernel(
    const float* __restrict__ sp_W, const float* __restrict__ sp_b,
    const float* __restrict__ zp_b, const float* __restrict__ aW,
    const float* __restrict__ ab,
    float* __restrict__ C, float* __restrict__ k0c, float* __restrict__ k1c)
{
  const int li = (int)blockIdx.x;          // ex*NLDn + l
  const int ex = li / NLDn;
  const int c2 = (int)threadIdx.x;         // 0..255
  const float* W   = aW + (size_t)(li * 2 + 1) * Dn * 384 + Dn;  // k,v columns
  const float* bb  = ab + (size_t)(li * 2 + 1) * 384 + Dn;
  const float* spw = sp_W + ex * SDn * Dn;
  const float* spb = sp_b + ex * Dn;
  const float* zpb = zp_b + ex * Dn;
  float acc[SDn];
#pragma unroll
  for (int k = 0; k < SDn; ++k) acc[k] = 0.f;
  float a0 = 0.f, a1 = 0.f;
  for (int d = 0; d < Dn; ++d) {
    const float w = W[(size_t)d * 384 + c2];
#pragma unroll
    for (int k = 0; k < SDn; ++k) acc[k] = fmaf(spw[k * Dn + d], w, acc[k]);
    a0 = fmaf(spb[d], w, a0);
    a1 = fmaf(zpb[d], w, a1);
  }
#pragma unroll
  for (int k = 0; k < SDn; ++k) C[((size_t)li * SDn + k) * 256 + c2] = acc[k];
  k0c[li * 256 + c2] = bb[c2] + a0;
  k1c[li * 256 + c2] = bb[c2] + a1;
}

// grouped GEMM, K=128 (packed A, 4 k-tiles).  grid (NBGMAX, 2): y = M-half.
// EPI 0: store bf16 row-major (stride obstr)   [QKV / cross-Q]
// EPI 4: fused norm_first epilogue: v = c + bias + X; X = v (RAW);
//        packed A = LN(v) with (lnsA,lnbA,subOff)           [O-proj]
template<int NTW, int EPI, bool HASB>
__global__ __launch_bounds__(256) void gemm_k128(
    const short* __restrict__ A, const short* __restrict__ Bb, const int strideB,
    const float* __restrict__ biasb, const int strideBias, const int ntOff,
    short* __restrict__ OutBf, const int obstr, short* __restrict__ OutP,
    const float* __restrict__ lnsA, const float* __restrict__ lnbA, const int subOff,
    float* __restrict__ X, const int* __restrict__ sch)
{
  __shared__ float red[16][4][2];
  const int k = (int)blockIdx.x;
  if (k >= sch[0]) return;
  const int ex  = sch[GEXP_OFF + k];
  const int mt0 = sch[GMT_OFF + k] + (int)blockIdx.y * 4;
  const short* Bp = Bb + (size_t)ex * strideB;
  const float* bias = biasb + (size_t)ex * strideBias;
  const float* gs = (EPI == 4) ? lnsA + ex * (NLDn * 3 * 128) + subOff : nullptr;
  const float* gb = (EPI == 4) ? lnbA + ex * (NLDn * 3 * 128) + subOff : nullptr;
  const int lane = (int)threadIdx.x & 63, wv = (int)threadIdx.x >> 6;
  const int r0 = lane & 15, g = lane >> 4;
  short8 bf[NTW][4];
#pragma unroll
  for (int i = 0; i < NTW; ++i)
#pragma unroll
    for (int kt = 0; kt < 4; ++kt)
      bf[i][kt] = *reinterpret_cast<const short8*>(
          Bp + (((size_t)(ntOff + wv * NTW + i) * 4 + kt) * 64 + lane) * 8);
  for (int mt = 0; mt < 4; ++mt) {
    short8 a[4];
#pragma unroll
    for (int kt = 0; kt < 4; ++kt)
      a[kt] = *reinterpret_cast<const short8*>(
          A + (((size_t)(mt0 + mt) * 4 + kt) * 64 + lane) * 8);
    float v[NTW][4];
#pragma unroll
    for (int i = 0; i < NTW; ++i) {
      f32x4v c = {0.f, 0.f, 0.f, 0.f};
#pragma unroll
      for (int kt = 0; kt < 4; ++kt)
        c = __builtin_amdgcn_mfma_f32_16x16x32_bf16(a[kt], bf[i][kt], c, 0, 0, 0);
      const int colL = (wv * NTW + i) * 16 + r0;
      const float bb = HASB ? bias[colL] : 0.f;
      const int rowB = (mt0 + mt) * 16 + g * 4;
#pragma unroll
      for (int q = 0; q < 4; ++q) {
        const int row = rowB + q;
        const float val = c[q] + bb;
        if (EPI == 0) {
          OutBf[(size_t)row * obstr + colL] = f2bf(val);
        } else {
          v[i][q] = val + X[(size_t)row * 128 + colL];
        }
      }
    }
    if (EPI == 4) {
      float s1[4], s2[4];
#pragma unroll
      for (int q = 0; q < 4; ++q) {
        s1[q] = v[0][q] + v[1][q];
        s2[q] = v[0][q] * v[0][q] + v[1][q] * v[1][q];
      }
#pragma unroll
      for (int o = 1; o < 16; o <<= 1)
#pragma unroll
        for (int q = 0; q < 4; ++q) { s1[q] += __shfl_xor(s1[q], o); s2[q] += __shfl_xor(s2[q], o); }
      if (r0 == 0)
#pragma unroll
        for (int q = 0; q < 4; ++q) { red[g * 4 + q][wv][0] = s1[q]; red[g * 4 + q][wv][1] = s2[q]; }
      __syncthreads();
#pragma unroll
      for (int q = 0; q < 4; ++q) {
        const int r = g * 4 + q;
        const float t1 = red[r][0][0] + red[r][1][0] + red[r][2][0] + red[r][3][0];
        const float t2 = red[r][0][1] + red[r][1][1] + red[r][2][1] + red[r][3][1];
        const float m  = t1 * (1.f / 128.f);
        const float rs = rsqrtf(t2 * (1.f / 128.f) - m * m + 1e-5f);
        const int row = (mt0 + mt) * 16 + r;
#pragma unroll
        for (int i = 0; i < 2; ++i) {
          const int col = (wv * 2 + i) * 16 + r0;
          const float o = (v[i][q] - m) * rs * gs[col] + gb[col];
          X[(size_t)row * 128 + col] = v[i][q];   // norm_first: RAW residual
          OutP[apos(row, col, 4)] = f2bf(o);      // LN'd input for next phase
        }
      }
      __syncthreads();
    }
  }
}

// fused expert FFN: H = relu(A@W1+b1) in LDS (single bf16); v = X + H@W2 + b2;
// DOLN: X = v raw, packed A = LN(v); else X = v.  512 thr, grid (NBGMAX, 2).
// B-tile loads double-buffered (1-deep) in both phases; MFMA order unchanged.
#define EFFN_LOADW1(ii, BW)                                                 \
  {                                                                         \
    const int nt_ = wv * 4 + (ii);                                          \
    for (int kt = 0; kt < 4; ++kt)                                          \
      BW[kt] = *reinterpret_cast<const short8*>(                            \
          W1p + (((size_t)(nt_ * 4 + kt) * 64 + lane)) * 8);                \
  }
#define EFFN_COMP1(ii, BW)                                                  \
  {                                                                         \
    const int nt_ = wv * 4 + (ii);                                          \
    const int col_ = nt_ * 16 + r0;                                         \
    const float bb_ = b1[col_];                                             \
    for (int mtl = 0; mtl < 4; ++mtl) {                                     \
      f32x4v c = {0.f, 0.f, 0.f, 0.f};                                      \
      for (int kt = 0; kt < 4; ++kt)                                        \
        c = __builtin_amdgcn_mfma_f32_16x16x32_bf16(a[mtl][kt], BW[kt], c, 0, 0, 0); \
      for (int q = 0; q < 4; ++q) {                                         \
        const int rl_ = mtl * 16 + g * 4 + q;                               \
        HsL[hpos(rl_, col_)] = f2bf(fmaxf(c[q] + bb_, 0.f));                \
      }                                                                     \
    }                                                                       \
  }
#define EFFN_LOADW2(kk, BW)                                                 \
  {                                                                         \
    BW = *reinterpret_cast<const short8*>(                                  \
        W2p + (((size_t)(wv * 16 + (kk)) * 64 + lane)) * 8);                \
  }
#define EFFN_COMP2(kk, BW)                                                  \
  {                                                                         \
    for (int mtl = 0; mtl < 4; ++mtl) {                                     \
      const short8 aw_ = *reinterpret_cast<const short8*>(                  \
          HsL + (((size_t)(mtl * 16 + (kk)) * 64 + lane)) * 8);             \
      c2[mtl] = __builtin_amdgcn_mfma_f32_16x16x32_bf16(aw_, BW, c2[mtl], 0, 0, 0); \
    }                                                                       \
  }

template<bool DOLN>
__global__ __launch_bounds__(512) void effn_kernel(
    const short* __restrict__ A, const short* __restrict__ W1b, const int strideW1,
    const float* __restrict__ b1b, const int strideB1,
    const short* __restrict__ W2b, const int strideW2,
    const float* __restrict__ b2b, const int strideB2,
    float* __restrict__ X, short* __restrict__ OutP,
    const float* __restrict__ lnsA, const float* __restrict__ lnbA, const int subOff,
    const int* __restrict__ sch)
{
  __shared__ short HsL[4 * 16 * 64 * 8];   // 64 KB, 64 rows x 512 cols bf16 packed
  __shared__ float red[16][8][2];
  const int k = (int)blockIdx.x;
  if (k >= sch[0]) return;
  const int ex  = sch[GEXP_OFF + k];
  const int mt0 = sch[GMT_OFF + k] + (int)blockIdx.y * 4;
  const short* W1p = W1b + (size_t)ex * strideW1;
  const short* W2p = W2b + (size_t)ex * strideW2;
  const float* b1 = b1b + (size_t)ex * strideB1;
  const float* b2 = b2b + (size_t)ex * strideB2;
  const float* gs = DOLN ? lnsA + ex * (NLDn * 3 * 128) + subOff : nullptr;
  const float* gb = DOLN ? lnbA + ex * (NLDn * 3 * 128) + subOff : nullptr;
  const int lane = (int)threadIdx.x & 63, wv = (int)threadIdx.x >> 6;  // 8 waves
  const int r0 = lane & 15, g = lane >> 4;
  // persistent A fragments (4 local M-tiles)
  short8 a[4][4];
#pragma unroll
  for (int mtl = 0; mtl < 4; ++mtl)
#pragma unroll
    for (int kt = 0; kt < 4; ++kt)
      a[mtl][kt] = *reinterpret_cast<const short8*>(
          A + (((size_t)(mt0 + mtl) * 4 + kt) * 64 + lane) * 8);
  // phase 1: W1 + relu -> LDS (single bf16), double-buffered W1 tiles
  {
    short8 bwA[4], bwB[4];
    EFFN_LOADW1(0, bwA)
    EFFN_LOADW1(1, bwB)
    EFFN_COMP1(0, bwA)
    EFFN_LOADW1(2, bwA)
    EFFN_COMP1(1, bwB)
    EFFN_LOADW1(3, bwB)
    EFFN_COMP1(2, bwA)
    EFFN_COMP1(3, bwB)
  }
  __syncthreads();
  // phase 2: H@W2 (K=512 from LDS), double-buffered W2 tiles
  const int col = wv * 16 + r0;
  f32x4v c2[4];
#pragma unroll
  for (int mtl = 0; mtl < 4; ++mtl) c2[mtl] = (f32x4v){0.f, 0.f, 0.f, 0.f};
  {
    short8 w2A, w2B;
    EFFN_LOADW2(0, w2A)
    EFFN_LOADW2(1, w2B)
#pragma unroll
    for (int kk = 0; kk < 16; kk += 2) {
      EFFN_COMP2(kk, w2A)
      if (kk + 2 < 16) EFFN_LOADW2(kk + 2, w2A)
      EFFN_COMP2(kk + 1, w2B)
      if (kk + 3 < 16) EFFN_LOADW2(kk + 3, w2B)
    }
  }
  const float bb2 = b2[col];
  for (int mtl = 0; mtl < 4; ++mtl) {
    const int mtg = mt0 + mtl;
    float v[4];
#pragma unroll
    for (int q = 0; q < 4; ++q) {
      const int row = mtg * 16 + g * 4 + q;
      v[q] = c2[mtl][q] + bb2 + X[(size_t)row * 128 + col];
    }
    if (DOLN) {
      float s1[4], s2[4];
#pragma unroll
      for (int q = 0; q < 4; ++q) { s1[q] = v[q]; s2[q] = v[q] * v[q]; }
#pragma unroll
      for (int o = 1; o < 16; o <<= 1)
#pragma unroll
        for (int q = 0; q < 4; ++q) { s1[q] += __shfl_xor(s1[q], o); s2[q] += __shfl_xor(s2[q], o); }
      if (r0 == 0)
#pragma unroll
        for (int q = 0; q < 4; ++q) { red[g * 4 + q][wv][0] = s1[q]; red[g * 4 + q][wv][1] = s2[q]; }
      __syncthreads();
#pragma unroll
      for (int q = 0; q < 4; ++q) {
        const int r = g * 4 + q;
        float t1 = 0.f, t2 = 0.f;
#pragma unroll
        for (int w = 0; w < 8; ++w) { t1 += red[r][w][0]; t2 += red[r][w][1]; }
        const float m  = t1 * (1.f / 128.f);
        const float rs = rsqrtf(t2 * (1.f / 128.f) - m * m + 1e-5f);
        const int row = mtg * 16 + r;
        const float o = (v[q] - m) * rs * gs[col] + gb[col];
        X[(size_t)row * 128 + col] = v[q];      // norm_first: RAW residual
        OutP[apos(row, col, 4)] = f2bf(o);      // LN'd input for next layer
      }
      __syncthreads();
    } else {
#pragma unroll
      for (int q = 0; q < 4; ++q) {
        const int row = mtg * 16 + g * 4 + q;
        X[(size_t)row * 128 + col] = v[q];
      }
    }
  }
}

// per (pair, head) self-attention: QKV bf16 (stride 384) -> O packed bf16.
// grid (4096, 4), 64 threads. Wave-parallel softmax, norm folded into AV.
__global__ __launch_bounds__(64) void sattn_kernel(
    const short* __restrict__ QKVb, const int* __restrict__ prow,
    short* __restrict__ ANP)
{
  __shared__ float qs[CSn * HSTR], ks[CSn * HSTR], vs[CSn * HSTR];
  __shared__ float att[CSn * CSn];
  __shared__ float inv[CSn];
  const int i = (int)blockIdx.x, h = (int)blockIdx.y;
  const int tid = (int)threadIdx.x;
  const int row0 = prow[i];
  for (int u = tid; u < CSn * 12; u += 64) {
    const int il = u / 12, r = u % 12, which = r >> 2, d8 = r & 3;
    const short8 s = *reinterpret_cast<const short8*>(
        QKVb + (size_t)(row0 + il) * 384 + which * 128 + h * 32 + d8 * 8);
    float* dst = (which == 0 ? qs : which == 1 ? ks : vs) + il * HSTR + d8 * 8;
#pragma unroll
    for (int u8 = 0; u8 < 8; ++u8) dst[u8] = bf2f(s[u8]);
  }
  __syncthreads();
  for (int e = tid; e < CSn * CSn; e += 64) {
    const int ii = e / CSn, j = e % CSn;
    const float* qp = qs + ii * HSTR;
    const float* kp = ks + j * HSTR;
    float acc = 0.f;
#pragma unroll
    for (int d = 0; d < DHn; d += 4) {
      const float4 qa = *reinterpret_cast<const float4*>(qp + d);
      const float4 kb = *reinterpret_cast<const float4*>(kp + d);
      acc += qa.x * kb.x + qa.y * kb.y + qa.z * kb.z + qa.w * kb.w;
    }
    att[e] = acc * INV_SQRT_DH;
  }
  __syncthreads();
  if (tid < 2 * CSn) {                 // 40 lanes: 2 per row, 10 elems each
    const int r = tid >> 1, h0 = (tid & 1) * 10;
    float* row = att + r * CSn + h0;
    float m = row[0];
#pragma unroll
    for (int j = 1; j < 10; ++j) m = fmaxf(m, row[j]);
    m = fmaxf(m, __shfl_xor(m, 1));
    float s = 0.f;
#pragma unroll
    for (int j = 0; j < 10; ++j) { const float ex = expf(row[j] - m); row[j] = ex; s += ex; }
    s += __shfl_xor(s, 1);
    if ((tid & 1) == 0) inv[r] = 1.f / s;
  }
  __syncthreads();
  for (int e = tid; e < CSn * 32; e += 64) {
    const int ii = e >> 5, c = e & 31;
    const float* arow = att + ii * CSn;
    float acc = 0.f;
#pragma unroll 4
    for (int j = 0; j < CSn; ++j) acc = fmaf(arow[j], vs[j * HSTR + c], acc);
    acc *= inv[ii];
    ANP[apos(row0 + ii, h * 32 + c, 4)] = f2bf(acc);
  }
}

// per-pair cross-attention (2 keys): Qc bf16 (stride 128) + composite memkv
__global__ __launch_bounds__(256) void cattn_kernel(
    const short* __restrict__ Qb, const float* __restrict__ state,
    const float* __restrict__ C, const float* __restrict__ k0c,
    const float* __restrict__ k1c, const int layer,
    const int* __restrict__ plist, const int* __restrict__ prow,
    const int* __restrict__ pexp, short* __restrict__ ANP)
{
  __shared__ float q[CSn * Dn];
  __shared__ float memkv[2 * 256];
  __shared__ float catt[2 * Hn * CSn];
  __shared__ float st[SDn];
  const int i = (int)blockIdx.x;
  const int ex = pexp[i];
  const int b = plist[i] >> 1;
  const int li = ex * NLDn + layer;
  const int row0 = prow[i];
  const int tid = (int)threadIdx.x;

  if (tid < SDn) st[tid] = state[b * SDn + tid];
  for (int e8 = tid; e8 < CSn * 16; e8 += 256) {
    const int il = e8 >> 4, c8 = e8 & 15;
    const short8 s = *reinterpret_cast<const short8*>(
        Qb + (size_t)(row0 + il) * 128 + c8 * 8);
    float* dst = q + il * Dn + c8 * 8;
#pragma unroll
    for (int u = 0; u < 8; ++u) dst[u] = bf2f(s[u]);
  }
  __syncthreads();
  {
    const int c2 = tid;                       // 256 threads, one column each
    float acc = k0c[li * 256 + c2];
#pragma unroll
    for (int k = 0; k < SDn; ++k)
      acc = fmaf(st[k], C[((size_t)li * SDn + k) * 256 + c2], acc);
    memkv[c2] = acc;
    memkv[256 + c2] = k1c[li * 256 + c2];
  }
  __syncthreads();
  for (int e = tid; e < Hn * CSn; e += 256) {
    const int h = e / CSn, il = e % CSn;
    const float* qp = q + il * Dn + h * DHn;
    float s0 = 0.f, s1 = 0.f;
#pragma unroll
    for (int d = 0; d < DHn; d += 4) {
      const float4 q4 = *reinterpret_cast<const float4*>(qp + d);
      const float4 k0 = *reinterpret_cast<const float4*>(memkv + 0 * 256 + h * DHn + d);
      const float4 k1 = *reinterpret_cast<const float4*>(memkv + 1 * 256 + h * DHn + d);
      s0 += q4.x * k0.x + q4.y * k0.y + q4.z * k0.z + q4.w * k0.w;
      s1 += q4.x * k1.x + q4.y * k1.y + q4.z * k1.z + q4.w * k1.w;
    }
    s0 *= INV_SQRT_DH; s1 *= INV_SQRT_DH;
    const float m = fmaxf(s0, s1);
    const float e0 = expf(s0 - m), e1 = expf(s1 - m);
    const float inv = 1.f / (e0 + e1);
    catt[e * 2] = e0 * inv; catt[e * 2 + 1] = e1 * inv;
  }
  __syncthreads();
  for (int e = tid; e < CSn * Dn; e += 256) {
    const int il = e >> 7, c = e & 127, h = c >> 5;
    const int a = (h * CSn + il) * 2;
    const float v = catt[a]     * memkv[0 * 256 + Dn + c]
                  + catt[a + 1] * memkv[1 * 256 + Dn + c];
    ANP[apos(row0 + il, c, 4)] = f2bf(v);
  }
}

__global__ __launch_bounds__(256) void head_kernel(
    const float* __restrict__ X, const int* __restrict__ plist,
    const int* __restrict__ prow, const int* __restrict__ pexp,
    const float* __restrict__ rwgt, const float* __restrict__ hW,
    const float* __restrict__ hb, float* __restrict__ Rbuf)
{
  __shared__ float xr[CSn * Dn];
  const int i = (int)blockIdx.x;
  const int ex = pexp[i];
  const int orig = plist[i];
  const int row0 = prow[i];
  const float wgt = rwgt[orig];
  for (int e4 = (int)threadIdx.x; e4 < CSn * 32; e4 += 256) {
    const int il = e4 >> 5, c4 = (e4 & 31) * 4;
    *reinterpret_cast<float4*>(xr + il * Dn + c4) =
        *reinterpret_cast<const float4*>(X + (size_t)(row0 + il) * 128 + c4);
  }
  __syncthreads();
  const int e = (int)threadIdx.x;
  if (e < CSn * JDn) {
    const int t = e / JDn, j = e - t * JDn;
    const float* w = hW + ex * Dn * JDn + j;
    float acc = hb[ex * JDn + j];
#pragma unroll 4
    for (int kk = 0; kk < Dn; ++kk) acc = fmaf(xr[t * Dn + kk], w[kk * JDn], acc);
    Rbuf[(size_t)i * 140 + e] = wgt * acc;
  }
}

__global__ void combine_kernel(const float* __restrict__ Rbuf,
                               const int* __restrict__ ppos, float* __restrict__ out)
{
  const int idx = (int)blockIdx.x * 256 + (int)threadIdx.x;
  if (idx >= Bn * 140) return;
  const int b = idx / 140, e = idx - b * 140;
  out[idx] = Rbuf[(size_t)ppos[2 * b] * 140 + e] + Rbuf[(size_t)ppos[2 * b + 1] * 140 + e];
}

// ---------------------------------------------------------------------------
__global__ void qpe_kernel(float* qpe)
{
  const int e = (int)blockIdx.x * 256 + (int)threadIdx.x;
  if (e < CSn * Dn) {
    const int t = e >> 7, d = e & 127;
    const float j  = (float)(d & ~1);
    const float dv = expf(j * (-logf(10000.f) / 128.f));
    const float a  = (float)t * dv;
    qpe[e] = (d & 1) ? cosf(a) : sinf(a);
  }
}

} // namespace

// ---------------------------------------------------------------------------
extern "C" void kernel_launch(void* const* d_in, const int* in_sizes, int n_in,
                              void* d_out, int out_size, void* d_ws, size_t ws_size,
                              hipStream_t stream)
{
  (void)in_sizes; (void)n_in; (void)out_size;

  const int*   ids     = (const int*)  d_in[0];
  const float* state   = (const float*)d_in[1];
  const float* tok_emb = (const float*)d_in[2];
  const float* pos_emb = (const float*)d_in[3];

  // persistent workspace (256B-aligned cursor)
  char* cur = (char*)d_ws;
  auto alloc = [&cur](size_t bytes) -> char* {
    char* p = cur; cur += (bytes + 255) & ~(size_t)255; return p;
  };
  float* qpe    = (float*)alloc(4096 * 4);
  float* intent = (float*)alloc((size_t)Bn * Dn * 4);
  int*   ridx   = (int*)  alloc(PAIRS * 4);
  float* rwgt   = (float*)alloc(PAIRS * 4);
  short* pQ     = (short*)alloc((size_t)36 * 49152 * 2);   // expert packs (single bf16)
  short* pO     = (short*)alloc((size_t)36 * 16384 * 2);
  short* pF1    = (short*)alloc((size_t)18 * 65536 * 2);
  short* pF2    = (short*)alloc((size_t)18 * 65536 * 2);
  short* pbQ    = (short*)alloc((size_t)4 * 98304 * 2);    // BERT packs (split hi/lo)
  short* pbO    = (short*)alloc((size_t)4 * 32768 * 2);
  short* pbW1   = (short*)alloc((size_t)4 * 131072 * 2);
  short* pbW2   = (short*)alloc((size_t)4 * 131072 * 2);
  int*   sch    = (int*)  alloc(2048 * 4);
  int*   plist  = (int*)  alloc(PAIRS * 4);
  int*   prow   = (int*)  alloc(PAIRS * 4);
  int*   pexp   = (int*)  alloc(PAIRS * 4);
  int*   ppos   = (int*)  alloc(PAIRS * 4);
  float* Cmat   = (float*)alloc((size_t)18 * SDn * 256 * 4);  // 294912 B
  float* k0c    = (float*)alloc((size_t)18 * 256 * 4);
  float* k1c    = (float*)alloc((size_t)18 * 256 * 4);
  constexpr size_t ARENA_BYTES = 192806912;
  char* arena = alloc(ARENA_BYTES);
  if ((size_t)(cur - (char*)d_ws) > ws_size) return;  // ws confirmed sufficient R4-R13

  // BERT views
  float* Xb  = (float*)(arena);                          // 25.2 MB
  short* Ah  = (short*)(arena + 25165824);               // 12.6 MB
  short* Al  = (short*)(arena + 37748736);               // 12.6 MB
  float* SBb = (float*)(arena + 50331648);               // QKV fp32 75.5 MB
  // expert views
  float* X2   = (float*)(arena);                         // 42.3 MB
  short* ANP  = (short*)(arena + 42336256);              // 21.2 MB
  short* SBh  = (short*)(arena + 63504384);              // bf16 QKV/Qc
  float* Rbuf = (float*)(arena + 190513152);             // 2.3 MB

  qpe_kernel<<<dim3(10), dim3(256), 0, stream>>>(qpe);

  // ---- weight packing + composite cross-attn factors
  {
    const int tq = 36 * 6144;
    pack_kernel<<<dim3((tq + 255) / 256), dim3(256), 0, stream>>>(
        (const float*)d_in[34], pQ, 128, 384, tq);
    const int to = 36 * 2048;
    pack_kernel<<<dim3((to + 255) / 256), dim3(256), 0, stream>>>(
        (const float*)d_in[36], pO, 128, 128, to);
    const int t1c = 18 * 8192;
    pack_kernel<<<dim3((t1c + 255) / 256), dim3(256), 0, stream>>>(
        (const float*)d_in[40], pF1, 128, 512, t1c);
    const int t2c = 18 * 8192;
    pack_kernel<<<dim3((t2c + 255) / 256), dim3(256), 0, stream>>>(
        (const float*)d_in[42], pF2, 512, 128, t2c);
    const int bq = 4 * 6144;
    pack2_kernel<<<dim3((bq + 255) / 256), dim3(256), 0, stream>>>(
        (const float*)d_in[4], pbQ, 128, 384, bq);
    const int bo = 4 * 2048;
    pack2_kernel<<<dim3((bo + 255) / 256), dim3(256), 0, stream>>>(
        (const float*)d_in[6], pbO, 128, 128, bo);
    const int bw1 = 4 * 8192;
    pack2_kernel<<<dim3((bw1 + 255) / 256), dim3(256), 0, stream>>>(
        (const float*)d_in[8], pbW1, 128, 512, bw1);
    const int bw2 = 4 * 8192;
    pack2_kernel<<<dim3((bw2 + 255) / 256), dim3(256), 0, stream>>>(
        (const float*)d_in[10], pbW2, 512, 128, bw2);
    compose_kernel<<<dim3(En * NLDn), dim3(256), 0, stream>>>(
        (const float*)d_in[30], (const float*)d_in[31], (const float*)d_in[33],
        (const float*)d_in[34], (const float*)d_in[35], Cmat, k0c, k1c);
  }

  // ---- BERT phase pipeline (fused FFN)
  {
    const float* bq  = (const float*)d_in[5];
    const float* bo  = (const float*)d_in[7];
    const float* b1  = (const float*)d_in[9];
    const float* b2  = (const float*)d_in[11];
    const float* lns = (const float*)d_in[12];
    const float* lnb = (const float*)d_in[13];

    bembed_kernel<<<dim3(ROWSB / 16), dim3(256), 0, stream>>>(
        ids, tok_emb, pos_emb, Xb, Ah, Al);
    for (int l = 0; l < NLBn; ++l) {
      bqkv_kernel<<<dim3(ROWSB / 64, 3), dim3(256), 0, stream>>>(
          Ah, Al, pbQ + (size_t)l * 98304, bq + l * 384, SBb);
      battn_kernel<<<dim3(Bn, Hn), dim3(64), 0, stream>>>(SBb, ids, Ah, Al);
      bo_ln_kernel<<<dim3(ROWSB / 64), dim3(256), 0, stream>>>(
          Ah, Al, pbO + (size_t)l * 32768, bo + l * 128,
          lns + l * 256, lnb + l * 256, Xb, Ah, Al);
      bffn_kernel<<<dim3(ROWSB / 32), dim3(512), 0, stream>>>(
          Ah, Al, pbW1 + (size_t)l * 131072, pbW2 + (size_t)l * 131072,
          b1 + l * 512, b2 + l * 128,
          lns + l * 256 + 128, lnb + l * 256 + 128, Xb, Ah, Al);
    }
    bintent_kernel<<<dim3(Bn / 4), dim3(256), 0, stream>>>(
        Xb, (const float*)d_in[14], (const float*)d_in[15], intent);
  }

  // ---- router
  {
    RouterP rp;
    rp.state = state; rp.intent = intent;
    rp.se_W1 = (const float*)d_in[16]; rp.se_b1 = (const float*)d_in[17];
    rp.se_W2 = (const float*)d_in[18]; rp.se_b2 = (const float*)d_in[19];
    rp.se_ln_s = (const float*)d_in[20]; rp.se_ln_b = (const float*)d_in[21];
    rp.r_W1 = (const float*)d_in[22]; rp.r_b1 = (const float*)d_in[23];
    rp.r_W2 = (const float*)d_in[24]; rp.r_b2 = (const float*)d_in[25];
    rp.r_ln_s = (const float*)d_in[26]; rp.r_ln_b = (const float*)d_in[27];
    rp.gate_W = (const float*)d_in[28]; rp.gate_b = (const float*)d_in[29];
    rp.ridx = ridx; rp.rwgt = rwgt;
    router_kernel<<<dim3(Bn), dim3(128), 0, stream>>>(rp);
  }

  const float* ab   = (const float*)d_in[35];
  const float* abo  = (const float*)d_in[37];
  const float* lnsA = (const float*)d_in[38];
  const float* lnbA = (const float*)d_in[39];
  const float* fb1A = (const float*)d_in[41];
  const float* fb2A = (const float*)d_in[43];
  const float* hW   = (const float*)d_in[44];
  const float* hB   = (const float*)d_in[45];

  // ---- expert phase pipeline (fused FFN; grouped GEMMs M-split gridDim.y=2)
  {
    sched_kernel<<<dim3(1), dim3(256), 0, stream>>>(ridx, sch, plist, prow, pexp, ppos);
    xinit_kernel<<<dim3(MPMAX * 32 / 256), dim3(256), 0, stream>>>(qpe, sch, X2);
    ln_pack_kernel<<<dim3(MPMAX / 16), dim3(256), 0, stream>>>(
        X2, ANP, lnsA, lnbA, 0, sch);
    for (int l = 0; l < NLDn; ++l) {
      // self-attention block
      gemm_k128<6, 0, true><<<dim3(NBGMAX, 2), dim3(256), 0, stream>>>(
          ANP, pQ + (l * 2 + 0) * 49152, 294912,
          ab + (l * 2 + 0) * 384, 2304, 0,
          SBh, 384, nullptr, nullptr, nullptr, 0, nullptr, sch);
      sattn_kernel<<<dim3(PAIRS, Hn), dim3(64), 0, stream>>>(SBh, prow, ANP);
      gemm_k128<2, 4, true><<<dim3(NBGMAX, 2), dim3(256), 0, stream>>>(
          ANP, pO + (l * 2 + 0) * 16384, 98304,
          abo + (l * 2 + 0) * 128, 768, 0,
          nullptr, 0, ANP, lnsA, lnbA, (l * 3 + 1) * 128, X2, sch);
      // cross-attention block
      gemm_k128<2, 0, true><<<dim3(NBGMAX, 2), dim3(256), 0, stream>>>(
          ANP, pQ + (l * 2 + 1) * 49152, 294912,
          ab + (l * 2 + 1) * 384, 2304, 0,
          SBh, 128, nullptr, nullptr, nullptr, 0, nullptr, sch);
      cattn_kernel<<<dim3(PAIRS), dim3(256), 0, stream>>>(
          SBh, state, Cmat, k0c, k1c, l, plist, prow, pexp, ANP);
      gemm_k128<2, 4, true><<<dim3(NBGMAX, 2), dim3(256), 0, stream>>>(
          ANP, pO + (l * 2 + 1) * 16384, 98304,
          abo + (l * 2 + 1) * 128, 768, 0,
          nullptr, 0, ANP, lnsA, lnbA, (l * 3 + 2) * 128, X2, sch);
      // fused FFN (W1 + relu + W2 in one kernel, H in LDS)
      if (l < NLDn - 1) {
        effn_kernel<true><<<dim3(NBGMAX, 2), dim3(512), 0, stream>>>(
            ANP, pF1 + l * 65536, 196608, fb1A + l * 512, 1536,
            pF2 + l * 65536, 196608, fb2A + l * 128, 384,
            X2, ANP, lnsA, lnbA, ((l + 1) * 3 + 0) * 128, sch);
      } else {
        effn_kernel<false><<<dim3(NBGMAX, 2), dim3(512), 0, stream>>>(
            ANP, pF1 + l * 65536, 196608, fb1A + l * 512, 1536,
            pF2 + l * 65536, 196608, fb2A + l * 128, 384,
            X2, nullptr, nullptr, nullptr, 0, sch);
      }
    }
    head_kernel<<<dim3(PAIRS), dim3(256), 0, stream>>>(
        X2, plist, prow, pexp, rwgt, hW, hB, Rbuf);
    combine_kernel<<<dim3((Bn * 140 + 255) / 256), dim3(256), 0, stream>>>(
        Rbuf, ppos, (float*)d_out);
  }
}

// Round 15
// 1408.715 us; speedup vs baseline: 1.0567x; 1.0567x over previous
//
#include <hip/hip_runtime.h>
#include <math.h>

#define DEVI __device__ __forceinline__

namespace {

constexpr int Bn   = 2048;
constexpr int En   = 6;
constexpr int Hn   = 4;
constexpr int Dn   = 128;
constexpr int DHn  = 32;
constexpr int LTn  = 24;   // text length
constexpr int CSn  = 20;   // chunk (decoder query) length
constexpr int JDn  = 7;
constexpr int SDn  = 16;
constexpr int NLBn = 4;
constexpr int NLDn = 3;
constexpr int DFFn = 512;
constexpr float INV_SQRT_DH = 0.17677669529663687f;  // 1/sqrt(32)

// expert phase-pipeline geometry
constexpr int PAIRS  = 4096;                  // 2048 items x top-2
constexpr int MPMAX  = PAIRS * 20 + En * 128; // padded rows (per-expert 128-aligned)
constexpr int NBGMAX = PAIRS * 20 / 128 + En; // 646 grouped-GEMM blocks max
constexpr int GEXP_OFF = 64;
constexpr int GMT_OFF  = 64 + NBGMAX;

// BERT pipeline geometry
constexpr int ROWSB = Bn * LTn;               // 49152 rows, 3072 M-tiles, no padding

// per-head attention LDS stride (36 mod 32 = 4 -> conflict-light, 16B-aligned)
constexpr int HSTR = 36;

typedef float f32x4v __attribute__((ext_vector_type(4)));
typedef short short8 __attribute__((ext_vector_type(8)));

DEVI float geluf(float x) { return 0.5f * x * (1.0f + erff(x * 0.70710678118654752f)); }

DEVI short f2bf(float f) {  // fp32 -> bf16 bits, round-to-nearest-even
  unsigned u = __float_as_uint(f);
  return (short)((u + 0x7FFFu + ((u >> 16) & 1u)) >> 16);
}
DEVI float bf2f(short s) { return __uint_as_float(((unsigned)(unsigned short)s) << 16); }
DEVI void split2(float v, short& h, short& l) {  // v ~= hi + lo to ~2^-16 rel
  h = f2bf(v);
  l = f2bf(v - bf2f(h));
}

// packed-A position for (row, col), K-tile count KT
DEVI size_t apos(int row, int col, int KT) {
  return (((size_t)(row >> 4) * KT + (col >> 5)) * 64 + ((col >> 3) & 3) * 16 + (row & 15)) * 8
         + (col & 7);
}

// local packed-H position (row local rl, col in [0,512), KT=16)
DEVI size_t hpos(int rl, int col) {
  return (((size_t)((rl >> 4) * 16 + (col >> 5)) * 64) + ((col >> 3) & 3) * 16 + (rl & 15)) * 8
         + (col & 7);
}

// ---------------------------------------------------------------------------
// pack fp32 [K][N] into single-bf16 B tiles (512 shorts/tile)
__global__ void pack_kernel(const float* __restrict__ W, short* __restrict__ out,
                            const int K, const int N, const int total)
{
  const int p = (int)blockIdx.x * 256 + (int)threadIdx.x;
  if (p >= total) return;
  const int perMat = (K * N) >> 3;
  const int m = p / perMat, r = p - m * perMat;
  const int t = r >> 6, lane = r & 63;
  const int KT = K >> 5;
  const int nt = t / KT, kt = t - nt * KT;
  const int row0 = kt * 32 + (lane >> 4) * 8;
  const int col  = nt * 16 + (lane & 15);
  const float* src = W + (size_t)m * K * N;
  short8 v;
#pragma unroll
  for (int j = 0; j < 8; ++j) v[j] = f2bf(src[(size_t)(row0 + j) * N + col]);
  *reinterpret_cast<short8*>(out + (size_t)p * 8) = v;
}

// pack fp32 [K][N] into split hi/lo B tiles (1024 shorts/tile)
__global__ void pack2_kernel(const float* __restrict__ W, short* __restrict__ out,
                             const int K, const int N, const int total)
{
  const int p = (int)blockIdx.x * 256 + (int)threadIdx.x;
  if (p >= total) return;
  const int perMat = (K * N) >> 3;
  const int m = p / perMat, r = p - m * perMat;
  const int t = r >> 6, lane = r & 63;
  const int KT = K >> 5;
  const int nt = t / KT, kt = t - nt * KT;
  const int row0 = kt * 32 + (lane >> 4) * 8;
  const int col  = nt * 16 + (lane & 15);
  const float* src = W + (size_t)m * K * N;
  short8 vh, vl;
#pragma unroll
  for (int j = 0; j < 8; ++j) {
    short hh, ll;
    split2(src[(size_t)(row0 + j) * N + col], hh, ll);
    vh[j] = hh; vl[j] = ll;
  }
  const size_t T  = (size_t)(perMat >> 6);
  const size_t tg = (size_t)m * T + t;
  *reinterpret_cast<short8*>(out + tg * 1024 + lane * 8)       = vh;
  *reinterpret_cast<short8*>(out + tg * 1024 + 512 + lane * 8) = vl;
}

// ===========================================================================
// BERT phase pipeline (split-bf16, M = 49152 rows)
// ===========================================================================

__global__ __launch_bounds__(256) void bembed_kernel(
    const int* __restrict__ ids, const float* __restrict__ tok,
    const float* __restrict__ pos, float* __restrict__ X,
    short* __restrict__ Ah, short* __restrict__ Al)
{
  const int mt = (int)blockIdx.x;          // 0..3071
  const int t = (int)threadIdx.x;
  const int rl = t >> 4, j = t & 15;
  const int row = mt * 16 + rl;
  const int b = row / 24, i = row - b * 24;
  const int id = ids[b * 24 + i];
  const float* tp = tok + (size_t)id * 128 + j * 8;
  const float* pp = pos + i * 128 + j * 8;
  float x[8];
  short8 vh, vl;
#pragma unroll
  for (int u = 0; u < 8; ++u) {
    x[u] = tp[u] + pp[u];
    short hh, ll; split2(x[u], hh, ll);
    vh[u] = hh; vl[u] = ll;
  }
  float4 f0 = {x[0], x[1], x[2], x[3]}, f1 = {x[4], x[5], x[6], x[7]};
  *reinterpret_cast<float4*>(X + (size_t)row * 128 + j * 8) = f0;
  *reinterpret_cast<float4*>(X + (size_t)row * 128 + j * 8 + 4) = f1;
  const size_t pk = (((size_t)mt * 4 + (j >> 2)) * 64 + (j & 3) * 16 + rl) * 8;
  *reinterpret_cast<short8*>(Ah + pk) = vh;
  *reinterpret_cast<short8*>(Al + pk) = vl;
}

__global__ __launch_bounds__(256) void bqkv_kernel(
    const short* __restrict__ Ah, const short* __restrict__ Al,
    const short* __restrict__ Bp, const float* __restrict__ bias,
    float* __restrict__ Out)
{
  const int mt0 = (int)blockIdx.x * 4;
  const int nc  = (int)blockIdx.y;
  const int lane = (int)threadIdx.x & 63, wv = (int)threadIdx.x >> 6;
  const int r0 = lane & 15, g = lane >> 4;
  short8 bh[2][4], bl[2][4];
#pragma unroll
  for (int i = 0; i < 2; ++i)
#pragma unroll
    for (int kt = 0; kt < 4; ++kt) {
      const short* tb = Bp + (((size_t)(nc * 8 + wv * 2 + i) * 4 + kt) << 10);
      bh[i][kt] = *reinterpret_cast<const short8*>(tb + lane * 8);
      bl[i][kt] = *reinterpret_cast<const short8*>(tb + 512 + lane * 8);
    }
#pragma unroll 2
  for (int mt = 0; mt < 4; ++mt) {
    const int mtg = mt0 + mt;
    short8 ah[4], al[4];
#pragma unroll
    for (int kt = 0; kt < 4; ++kt) {
      ah[kt] = *reinterpret_cast<const short8*>(Ah + (((size_t)mtg * 4 + kt) * 64 + lane) * 8);
      al[kt] = *reinterpret_cast<const short8*>(Al + (((size_t)mtg * 4 + kt) * 64 + lane) * 8);
    }
#pragma unroll
    for (int i = 0; i < 2; ++i) {
      f32x4v c = {0.f, 0.f, 0.f, 0.f};
#pragma unroll
      for (int kt = 0; kt < 4; ++kt) {
        c = __builtin_amdgcn_mfma_f32_16x16x32_bf16(ah[kt], bh[i][kt], c, 0, 0, 0);
        c = __builtin_amdgcn_mfma_f32_16x16x32_bf16(al[kt], bh[i][kt], c, 0, 0, 0);
        c = __builtin_amdgcn_mfma_f32_16x16x32_bf16(ah[kt], bl[i][kt], c, 0, 0, 0);
      }
      const int col = nc * 128 + (wv * 2 + i) * 16 + r0;
      const float bb = bias[col];
#pragma unroll
      for (int q = 0; q < 4; ++q)
        Out[(size_t)(mtg * 16 + g * 4 + q) * 384 + col] = c[q] + bb;
    }
  }
}

// per (item, head) BERT attention: QKV fp32 -> attn out split-packed A.
// grid (2048, 4), 64 threads. Wave-parallel softmax, norm folded into AV.
__global__ __launch_bounds__(64) void battn_kernel(
    const float* __restrict__ QKV, const int* __restrict__ ids,
    short* __restrict__ Ah, short* __restrict__ Al)
{
  __shared__ float qs[LTn * HSTR], ks[LTn * HSTR], vs[LTn * HSTR];
  __shared__ float att[LTn * LTn];
  __shared__ float inv[LTn];
  __shared__ int pad_s[LTn];
  const int b = (int)blockIdx.x, h = (int)blockIdx.y;
  const int tid = (int)threadIdx.x;
  const int row0 = b * LTn;
  for (int u = tid; u < LTn * 24; u += 64) {
    const int il = u / 24, r = u % 24, which = r >> 3, d4 = r & 7;
    const float4 v = *reinterpret_cast<const float4*>(
        QKV + (size_t)(row0 + il) * 384 + which * 128 + h * 32 + d4 * 4);
    float* dst = (which == 0 ? qs : which == 1 ? ks : vs) + il * HSTR + d4 * 4;
    *reinterpret_cast<float4*>(dst) = v;
  }
  if (tid < LTn) pad_s[tid] = (ids[row0 + tid] == 0) ? 1 : 0;
  __syncthreads();
  for (int e = tid; e < LTn * LTn; e += 64) {
    const int i = e / LTn, j = e % LTn;
    const float* qp = qs + i * HSTR;
    const float* kp = ks + j * HSTR;
    float acc = 0.f;
#pragma unroll
    for (int d = 0; d < DHn; d += 4) {
      const float4 qa = *reinterpret_cast<const float4*>(qp + d);
      const float4 kb = *reinterpret_cast<const float4*>(kp + d);
      acc += qa.x * kb.x + qa.y * kb.y + qa.z * kb.z + qa.w * kb.w;
    }
    acc *= INV_SQRT_DH;
    if (pad_s[j]) acc = -1e9f;
    att[e] = acc;
  }
  __syncthreads();
  if (tid < 2 * LTn) {                 // 48 lanes: 2 per row, 12 elems each
    const int r = tid >> 1, h0 = (tid & 1) * 12;
    float* row = att + r * LTn + h0;
    float m = row[0];
#pragma unroll
    for (int j = 1; j < 12; ++j) m = fmaxf(m, row[j]);
    m = fmaxf(m, __shfl_xor(m, 1));
    float s = 0.f;
#pragma unroll
    for (int j = 0; j < 12; ++j) { const float ex = expf(row[j] - m); row[j] = ex; s += ex; }
    s += __shfl_xor(s, 1);
    if ((tid & 1) == 0) inv[r] = 1.f / s;
  }
  __syncthreads();
  for (int e = tid; e < LTn * 32; e += 64) {
    const int i = e >> 5, c = e & 31;
    const float* arow = att + i * LTn;
    float acc = 0.f;
#pragma unroll 4
    for (int j = 0; j < LTn; ++j) acc = fmaf(arow[j], vs[j * HSTR + c], acc);
    acc *= inv[i];
    short hh, ll; split2(acc, hh, ll);
    const size_t pk = apos(row0 + i, h * 32 + c, 4);
    Ah[pk] = hh; Al[pk] = ll;
  }
}

__global__ __launch_bounds__(256) void bo_ln_kernel(
    const short* __restrict__ Ah, const short* __restrict__ Al,
    const short* __restrict__ Bp, const float* __restrict__ bo,
    const float* __restrict__ gs, const float* __restrict__ gb,
    float* __restrict__ X, short* __restrict__ OAh, short* __restrict__ OAl)
{
  __shared__ float red[16][4][2];
  const int mt0 = (int)blockIdx.x * 4;
  const int lane = (int)threadIdx.x & 63, wv = (int)threadIdx.x >> 6;
  const int r0 = lane & 15, g = lane >> 4;
  short8 bh[2][4], bl[2][4];
#pragma unroll
  for (int i = 0; i < 2; ++i)
#pragma unroll
    for (int kt = 0; kt < 4; ++kt) {
      const short* tb = Bp + (((size_t)(wv * 2 + i) * 4 + kt) << 10);
      bh[i][kt] = *reinterpret_cast<const short8*>(tb + lane * 8);
      bl[i][kt] = *reinterpret_cast<const short8*>(tb + 512 + lane * 8);
    }
  for (int mt = 0; mt < 4; ++mt) {
    const int mtg = mt0 + mt;
    short8 ah[4], al[4];
#pragma unroll
    for (int kt = 0; kt < 4; ++kt) {
      ah[kt] = *reinterpret_cast<const short8*>(Ah + (((size_t)mtg * 4 + kt) * 64 + lane) * 8);
      al[kt] = *reinterpret_cast<const short8*>(Al + (((size_t)mtg * 4 + kt) * 64 + lane) * 8);
    }
    float v[2][4];
#pragma unroll
    for (int i = 0; i < 2; ++i) {
      f32x4v c = {0.f, 0.f, 0.f, 0.f};
#pragma unroll
      for (int kt = 0; kt < 4; ++kt) {
        c = __builtin_amdgcn_mfma_f32_16x16x32_bf16(ah[kt], bh[i][kt], c, 0, 0, 0);
        c = __builtin_amdgcn_mfma_f32_16x16x32_bf16(al[kt], bh[i][kt], c, 0, 0, 0);
        c = __builtin_amdgcn_mfma_f32_16x16x32_bf16(ah[kt], bl[i][kt], c, 0, 0, 0);
      }
      const int col = (wv * 2 + i) * 16 + r0;
      const float bb = bo[col];
#pragma unroll
      for (int q = 0; q < 4; ++q) {
        const int row = mtg * 16 + g * 4 + q;
        v[i][q] = c[q] + bb + X[(size_t)row * 128 + col];
      }
    }
    float s1[4], s2[4];
#pragma unroll
    for (int q = 0; q < 4; ++q) {
      s1[q] = v[0][q] + v[1][q];
      s2[q] = v[0][q] * v[0][q] + v[1][q] * v[1][q];
    }
#pragma unroll
    for (int o = 1; o < 16; o <<= 1)
#pragma unroll
      for (int q = 0; q < 4; ++q) { s1[q] += __shfl_xor(s1[q], o); s2[q] += __shfl_xor(s2[q], o); }
    if (r0 == 0)
#pragma unroll
      for (int q = 0; q < 4; ++q) { red[g * 4 + q][wv][0] = s1[q]; red[g * 4 + q][wv][1] = s2[q]; }
    __syncthreads();
#pragma unroll
    for (int q = 0; q < 4; ++q) {
      const int r = g * 4 + q;
      const float t1 = red[r][0][0] + red[r][1][0] + red[r][2][0] + red[r][3][0];
      const float t2 = red[r][0][1] + red[r][1][1] + red[r][2][1] + red[r][3][1];
      const float m  = t1 * (1.f / 128.f);
      const float rs = rsqrtf(t2 * (1.f / 128.f) - m * m + 1e-5f);
      const int row = mtg * 16 + r;
#pragma unroll
      for (int i = 0; i < 2; ++i) {
        const int col = (wv * 2 + i) * 16 + r0;
        const float o = (v[i][q] - m) * rs * gs[col] + gb[col];
        X[(size_t)row * 128 + col] = o;   // post-LN: LN'd value IS the residual
        short hh, ll; split2(o, hh, ll);
        const size_t pk = apos(row, col, 4);
        OAh[pk] = hh; OAl[pk] = ll;
      }
    }
    __syncthreads();
  }
}

// fused BERT FFN: H = gelu(A@W1+b1) kept in LDS; X = LN(X + H@W2 + b2); pack A.
// 512 threads (8 waves), 32 rows/block, grid ROWSB/32 = 1536.
__global__ __launch_bounds__(512) void bffn_kernel(
    const short* __restrict__ Ah, const short* __restrict__ Al,
    const short* __restrict__ W1p, const short* __restrict__ W2p,
    const float* __restrict__ b1, const float* __restrict__ b2,
    const float* __restrict__ gs, const float* __restrict__ gb,
    float* __restrict__ X, short* __restrict__ OAh, short* __restrict__ OAl)
{
  __shared__ short HhL[2 * 16 * 64 * 8];   // 32 KB
  __shared__ short HlL[2 * 16 * 64 * 8];   // 32 KB
  __shared__ float red[16][8][2];
  const int mtg0 = (int)blockIdx.x * 2;
  const int lane = (int)threadIdx.x & 63, wv = (int)threadIdx.x >> 6;  // 8 waves
  const int r0 = lane & 15, g = lane >> 4;
  // persistent A fragments (2 local M-tiles)
  short8 ah[2][4], al[2][4];
#pragma unroll
  for (int mtl = 0; mtl < 2; ++mtl)
#pragma unroll
    for (int kt = 0; kt < 4; ++kt) {
      ah[mtl][kt] = *reinterpret_cast<const short8*>(
          Ah + (((size_t)(mtg0 + mtl) * 4 + kt) * 64 + lane) * 8);
      al[mtl][kt] = *reinterpret_cast<const short8*>(
          Al + (((size_t)(mtg0 + mtl) * 4 + kt) * 64 + lane) * 8);
    }
  // phase 1: W1 + gelu -> LDS (split)
#pragma unroll
  for (int i = 0; i < 4; ++i) {
    const int nt = wv * 4 + i;
    short8 bh[4], bl[4];
#pragma unroll
    for (int kt = 0; kt < 4; ++kt) {
      const short* tb = W1p + (((size_t)(nt * 4 + kt)) << 10);
      bh[kt] = *reinterpret_cast<const short8*>(tb + lane * 8);
      bl[kt] = *reinterpret_cast<const short8*>(tb + 512 + lane * 8);
    }
    const int col = nt * 16 + r0;
    const float bb = b1[col];
#pragma unroll
    for (int mtl = 0; mtl < 2; ++mtl) {
      f32x4v c = {0.f, 0.f, 0.f, 0.f};
#pragma unroll
      for (int kt = 0; kt < 4; ++kt) {
        c = __builtin_amdgcn_mfma_f32_16x16x32_bf16(ah[mtl][kt], bh[kt], c, 0, 0, 0);
        c = __builtin_amdgcn_mfma_f32_16x16x32_bf16(al[mtl][kt], bh[kt], c, 0, 0, 0);
        c = __builtin_amdgcn_mfma_f32_16x16x32_bf16(ah[mtl][kt], bl[kt], c, 0, 0, 0);
      }
#pragma unroll
      for (int q = 0; q < 4; ++q) {
        const int rl = mtl * 16 + g * 4 + q;
        short hh, ll; split2(geluf(c[q] + bb), hh, ll);
        const size_t hp = hpos(rl, col);
        HhL[hp] = hh; HlL[hp] = ll;
      }
    }
  }
  __syncthreads();
  // phase 2: H@W2 (K=512 from LDS) + residual + LN + pack
  const int col = wv * 16 + r0;
  f32x4v c2[2];
#pragma unroll
  for (int mtl = 0; mtl < 2; ++mtl) c2[mtl] = (f32x4v){0.f, 0.f, 0.f, 0.f};
#pragma unroll
  for (int kk = 0; kk < 16; ++kk) {
    const short* tb = W2p + (((size_t)(wv * 16 + kk)) << 10);
    const short8 b2h = *reinterpret_cast<const short8*>(tb + lane * 8);
    const short8 b2l = *reinterpret_cast<const short8*>(tb + 512 + lane * 8);
#pragma unroll
    for (int mtl = 0; mtl < 2; ++mtl) {
      const size_t ap = (((size_t)(mtl * 16 + kk) * 64 + lane)) * 8;
      const short8 a2h = *reinterpret_cast<const short8*>(HhL + ap);
      const short8 a2l = *reinterpret_cast<const short8*>(HlL + ap);
      c2[mtl] = __builtin_amdgcn_mfma_f32_16x16x32_bf16(a2h, b2h, c2[mtl], 0, 0, 0);
      c2[mtl] = __builtin_amdgcn_mfma_f32_16x16x32_bf16(a2l, b2h, c2[mtl], 0, 0, 0);
      c2[mtl] = __builtin_amdgcn_mfma_f32_16x16x32_bf16(a2h, b2l, c2[mtl], 0, 0, 0);
    }
  }
  const float bb2 = b2[col];
  for (int mtl = 0; mtl < 2; ++mtl) {
    const int mtg = mtg0 + mtl;
    float v[4], s1[4], s2[4];
#pragma unroll
    for (int q = 0; q < 4; ++q) {
      const int row = mtg * 16 + g * 4 + q;
      v[q] = c2[mtl][q] + bb2 + X[(size_t)row * 128 + col];
      s1[q] = v[q]; s2[q] = v[q] * v[q];
    }
#pragma unroll
    for (int o = 1; o < 16; o <<= 1)
#pragma unroll
      for (int q = 0; q < 4; ++q) { s1[q] += __shfl_xor(s1[q], o); s2[q] += __shfl_xor(s2[q], o); }
    if (r0 == 0)
#pragma unroll
      for (int q = 0; q < 4; ++q) { red[g * 4 + q][wv][0] = s1[q]; red[g * 4 + q][wv][1] = s2[q]; }
    __syncthreads();
#pragma unroll
    for (int q = 0; q < 4; ++q) {
      const int r = g * 4 + q;
      float t1 = 0.f, t2 = 0.f;
#pragma unroll
      for (int w = 0; w < 8; ++w) { t1 += red[r][w][0]; t2 += red[r][w][1]; }
      const float m  = t1 * (1.f / 128.f);
      const float rs = rsqrtf(t2 * (1.f / 128.f) - m * m + 1e-5f);
      const int row = mtg * 16 + r;
      const float o = (v[q] - m) * rs * gs[col] + gb[col];
      X[(size_t)row * 128 + col] = o;     // post-LN
      short hh, ll; split2(o, hh, ll);
      const size_t pk = apos(row, col, 4);
      OAh[pk] = hh; OAl[pk] = ll;
    }
    __syncthreads();
  }
}

__global__ __launch_bounds__(256) void bintent_kernel(
    const float* __restrict__ X, const float* __restrict__ lnf_s,
    const float* __restrict__ lnf_b, float* __restrict__ intent)
{
  const int w = (int)threadIdx.x >> 6, lane = (int)threadIdx.x & 63;
  const int b = (int)blockIdx.x * 4 + w;
  const float* xr = X + (size_t)b * LTn * 128;
  const float a0 = xr[lane], a1 = xr[lane + 64];
  float s1 = a0 + a1, s2 = a0 * a0 + a1 * a1;
#pragma unroll
  for (int o = 32; o > 0; o >>= 1) { s1 += __shfl_xor(s1, o); s2 += __shfl_xor(s2, o); }
  const float m  = s1 * (1.f / 128.f);
  const float rs = rsqrtf(s2 * (1.f / 128.f) - m * m + 1e-5f);
  intent[b * 128 + lane]      = (a0 - m) * rs * lnf_s[lane]      + lnf_b[lane];
  intent[b * 128 + lane + 64] = (a1 - m) * rs * lnf_s[lane + 64] + lnf_b[lane + 64];
}

// ---------------------------------------------------------------------------
struct RouterP {
  const float* state; const float* intent;
  const float* se_W1; const float* se_b1; const float* se_W2; const float* se_b2;
  const float* se_ln_s; const float* se_ln_b;
  const float* r_W1; const float* r_b1; const float* r_W2; const float* r_b2;
  const float* r_ln_s; const float* r_ln_b;
  const float* gate_W; const float* gate_b;
  int* ridx; float* rwgt;
};

DEVI void ln128(float* x, const float* gs, const float* gb, float* red)
{
  const int c = (int)threadIdx.x;      // blockDim == 128
  const float a = x[c];
  float s1 = a, s2 = a * a;
#pragma unroll
  for (int o = 32; o > 0; o >>= 1) { s1 += __shfl_xor(s1, o); s2 += __shfl_xor(s2, o); }
  const int wid = c >> 6;
  if ((c & 63) == 0) { red[wid * 2] = s1; red[wid * 2 + 1] = s2; }
  __syncthreads();
  s1 = red[0] + red[2]; s2 = red[1] + red[3];
  const float m  = s1 * (1.f / 128.f);
  const float rs = rsqrtf(s2 * (1.f / 128.f) - m * m + 1e-5f);
  __syncthreads();
  x[c] = (a - m) * rs * gs[c] + gb[c];
}

// 128-deep dot with 4 independent accumulator chains (latency fix)
DEVI float dot128i(const float* __restrict__ h, const float* __restrict__ W,
                   const int c, const int wstr)
{
  float a0 = 0.f, a1 = 0.f, a2 = 0.f, a3 = 0.f;
#pragma unroll 8
  for (int k = 0; k < 128; k += 4) {
    a0 = fmaf(h[k + 0], W[(k + 0) * wstr + c], a0);
    a1 = fmaf(h[k + 1], W[(k + 1) * wstr + c], a1);
    a2 = fmaf(h[k + 2], W[(k + 2) * wstr + c], a2);
    a3 = fmaf(h[k + 3], W[(k + 3) * wstr + c], a3);
  }
  return (a0 + a1) + (a2 + a3);
}

__global__ __launch_bounds__(128) void router_kernel(RouterP p)
{
  __shared__ float sstate[SDn];
  __shared__ float h1[Dn];
  __shared__ float vv[Dn];
  __shared__ float red[4];
  __shared__ float slog[En];
  const int b = blockIdx.x;
  const int c = (int)threadIdx.x;

  if (c < SDn) sstate[c] = p.state[b * SDn + c];
  __syncthreads();
  {
    float acc = p.se_b1[c];
#pragma unroll
    for (int k = 0; k < SDn; ++k) acc = fmaf(sstate[k], p.se_W1[k * Dn + c], acc);
    h1[c] = geluf(acc);
  }
  __syncthreads();
  vv[c] = p.se_b2[c] + dot128i(h1, p.se_W2, c, Dn);
  __syncthreads();
  ln128(vv, p.se_ln_s, p.se_ln_b, red);
  __syncthreads();
  {
    const float* ib = p.intent + b * Dn;
    float acc = p.r_b1[c] + dot128i(ib, p.r_W1, c, Dn)
                          + dot128i(vv, p.r_W1 + Dn * Dn, c, Dn);
    h1[c] = geluf(acc);
  }
  __syncthreads();
  vv[c] = p.r_b2[c] + dot128i(h1, p.r_W2, c, Dn);
  __syncthreads();
  ln128(vv, p.r_ln_s, p.r_ln_b, red);
  __syncthreads();
  if (c < En) slog[c] = p.gate_b[c] + dot128i(vv, p.gate_W, c, En);
  __syncthreads();
  if (c == 0) {
    int i0 = 0; float v0 = slog[0];
#pragma unroll
    for (int e2 = 1; e2 < En; ++e2) if (slog[e2] > v0) { v0 = slog[e2]; i0 = e2; }
    int i1 = -1; float v1 = -3.4e38f;
#pragma unroll
    for (int e2 = 0; e2 < En; ++e2) if (e2 != i0 && slog[e2] > v1) { v1 = slog[e2]; i1 = e2; }
    const float e1  = expf(v1 - v0);
    const float inv = 1.f / (1.f + e1);
    p.ridx[b * 2 + 0] = i0; p.ridx[b * 2 + 1] = i1;
    p.rwgt[b * 2 + 0] = inv; p.rwgt[b * 2 + 1] = e1 * inv;
  }
}

// ===========================================================================
// EXPERT PHASE PIPELINE — norm_first: X keeps RAW residual, packed A gets LN
// ===========================================================================

__global__ void sched_kernel(const int* __restrict__ ridx, int* __restrict__ sch,
                             int* plist, int* prow, int* pexp, int* ppos)
{
  __shared__ int scnt[En], scur[En], soff[En], srb[En + 1];
  const int t = (int)threadIdx.x;
  if (t < En) { scnt[t] = 0; scur[t] = 0; }
  __syncthreads();
  for (int p = t; p < PAIRS; p += 256) atomicAdd(&scnt[ridx[p]], 1);
  __syncthreads();
  if (t == 0) {
    int off = 0, rb = 0, k = 0;
    for (int e = 0; e < En; ++e) {
      soff[e] = off; srb[e] = rb;
      const int rows = scnt[e] * 20;
      const int nb = (rows + 127) >> 7;
      for (int q = 0; q < nb; ++q) {
        sch[GEXP_OFF + k] = e;
        sch[GMT_OFF + k]  = (rb >> 4) + q * 8;
        ++k;
      }
      off += scnt[e];
      rb += nb * 128;
    }
    srb[En] = rb;
    sch[0] = k;
    for (int e = 0; e < En; ++e) { sch[1 + e] = scnt[e]; sch[7 + e] = soff[e]; }
    for (int e = 0; e <= En; ++e) sch[13 + e] = srb[e];
  }
  __syncthreads();
  for (int p = t; p < PAIRS; p += 256) {
    const int e = ridx[p];
    const int pos = atomicAdd(&scur[e], 1);
    const int i = soff[e] + pos;
    plist[i] = p; ppos[p] = i; pexp[i] = e; prow[i] = srb[e] + pos * 20;
  }
}

__global__ void xinit_kernel(const float* __restrict__ qpe, const int* __restrict__ sch,
                             float* __restrict__ X)
{
  const int idx = (int)blockIdx.x * 256 + (int)threadIdx.x;  // quad index
  const int row = idx >> 5;
  if (row >= MPMAX) return;
  const int c4 = (idx & 31) * 4;
  const int* RB = sch + 13;
  float4 v = {0.f, 0.f, 0.f, 0.f};
  int e = 0;
  while (e < En && row >= RB[e + 1]) ++e;
  if (e < En) {
    const int local = row - RB[e];
    if (local < sch[1 + e] * 20) {
      const int r = local - (local / 20) * 20;
      v = *reinterpret_cast<const float4*>(qpe + r * 128 + c4);
    }
  }
  *reinterpret_cast<float4*>(X + (size_t)row * 128 + c4) = v;
}

// LN over X rows -> packed bf16 A-fragments (used once, layer-0 sub-0)
__global__ __launch_bounds__(256) void ln_pack_kernel(
    const float* __restrict__ X, short* __restrict__ XnP,
    const float* __restrict__ lns_all, const float* __restrict__ lnb_all,
    const int subOff, const int* __restrict__ sch)
{
  const int* RB = sch + 13;
  const int mt = (int)blockIdx.x;
  const int row0 = mt << 4;
  if (row0 >= RB[En]) return;
  int e = 0;
  while (e < En - 1 && row0 >= RB[e + 1]) ++e;
  const float* gs = lns_all + e * (NLDn * 3 * 128) + subOff;
  const float* gb = lnb_all + e * (NLDn * 3 * 128) + subOff;
  const int t = (int)threadIdx.x;
  const int rl = t >> 4, j = t & 15;
  const int row = row0 + rl;
  float x[8];
  {
    const float4 a = *reinterpret_cast<const float4*>(X + (size_t)row * 128 + j * 8);
    const float4 bq = *reinterpret_cast<const float4*>(X + (size_t)row * 128 + j * 8 + 4);
    x[0] = a.x; x[1] = a.y; x[2] = a.z; x[3] = a.w;
    x[4] = bq.x; x[5] = bq.y; x[6] = bq.z; x[7] = bq.w;
  }
  float s1 = 0.f, s2 = 0.f;
#pragma unroll
  for (int u = 0; u < 8; ++u) { s1 += x[u]; s2 += x[u] * x[u]; }
#pragma unroll
  for (int o = 1; o < 16; o <<= 1) { s1 += __shfl_xor(s1, o); s2 += __shfl_xor(s2, o); }
  const float m  = s1 * (1.f / 128.f);
  const float rs = rsqrtf(s2 * (1.f / 128.f) - m * m + 1e-5f);
  short8 pk;
#pragma unroll
  for (int u = 0; u < 8; ++u)
    pk[u] = f2bf((x[u] - m) * rs * gs[j * 8 + u] + gb[j * 8 + u]);
  const int kt = j >> 2, g = j & 3, lp = g * 16 + rl;
  *reinterpret_cast<short8*>(XnP + (((size_t)mt * 4 + kt) * 64 + lp) * 8) = pk;
}

// composite cross-attn K/V factors
__global__ __launch_bounds__(256) void compose_kernel(
    const float* __restrict__ sp_W, const float* __restrict__ sp_b,
    const float* __restrict__ zp_b, const float* __restrict__ aW,
    const float* __restrict__ ab,
    float* __restrict__ C, float* __restrict__ k0c, float* __restrict__ k1c)
{
  const int li = (int)blockIdx.x;          // ex*NLDn + l
  const int ex = li / NLDn;
  const int c2 = (int)threadIdx.x;         // 0..255
  const float* W   = aW + (size_t)(li * 2 + 1) * Dn * 384 + Dn;  // k,v columns
  const float* bb  = ab + (size_t)(li * 2 + 1) * 384 + Dn;
  const float* spw = sp_W + ex * SDn * Dn;
  const float* spb = sp_b + ex * Dn;
  const float* zpb = zp_b + ex * Dn;
  float acc[SDn];
#pragma unroll
  for (int k = 0; k < SDn; ++k) acc[k] = 0.f;
  float a0 = 0.f, a1 = 0.f;
  for (int d = 0; d < Dn; ++d) {
    const float w = W[(size_t)d * 384 + c2];
#pragma unroll
    for (int k = 0; k < SDn; ++k) acc[k] = fmaf(spw[k * Dn + d], w, acc[k]);
    a0 = fmaf(spb[d], w, a0);
    a1 = fmaf(zpb[d], w, a1);
  }
#pragma unroll
  for (int k = 0; k < SDn; ++k) C[((size_t)li * SDn + k) * 256 + c2] = acc[k];
  k0c[li * 256 + c2] = bb[c2] + a0;
  k1c[li * 256 + c2] = bb[c2] + a1;
}

// grouped GEMM, K=128 (packed A, 4 k-tiles).  grid (NBGMAX, 2): y = M-half.
// EPI 0: store bf16 row-major (stride obstr)   [QKV / cross-Q]
// EPI 4: fused norm_first epilogue: v = c + bias + X; X = v (RAW);
//        packed A = LN(v) with (lnsA,lnbA,subOff)           [O-proj]
template<int NTW, int EPI, bool HASB>
__global__ __launch_bounds__(256) void gemm_k128(
    const short* __restrict__ A, const short* __restrict__ Bb, const int strideB,
    const float* __restrict__ biasb, const int strideBias, const int ntOff,
    short* __restrict__ OutBf, const int obstr, short* __restrict__ OutP,
    const float* __restrict__ lnsA, const float* __restrict__ lnbA, const int subOff,
    float* __restrict__ X, const int* __restrict__ sch)
{
  __shared__ float red[16][4][2];
  const int k = (int)blockIdx.x;
  if (k >= sch[0]) return;
  const int ex  = sch[GEXP_OFF + k];
  const int mt0 = sch[GMT_OFF + k] + (int)blockIdx.y * 4;
  const short* Bp = Bb + (size_t)ex * strideB;
  const float* bias = biasb + (size_t)ex * strideBias;
  const float* gs = (EPI == 4) ? lnsA + ex * (NLDn * 3 * 128) + subOff : nullptr;
  const float* gb = (EPI == 4) ? lnbA + ex * (NLDn * 3 * 128) + subOff : nullptr;
  const int lane = (int)threadIdx.x & 63, wv = (int)threadIdx.x >> 6;
  const int r0 = lane & 15, g = lane >> 4;
  short8 bf[NTW][4];
#pragma unroll
  for (int i = 0; i < NTW; ++i)
#pragma unroll
    for (int kt = 0; kt < 4; ++kt)
      bf[i][kt] = *reinterpret_cast<const short8*>(
          Bp + (((size_t)(ntOff + wv * NTW + i) * 4 + kt) * 64 + lane) * 8);
  for (int mt = 0; mt < 4; ++mt) {
    short8 a[4];
#pragma unroll
    for (int kt = 0; kt < 4; ++kt)
      a[kt] = *reinterpret_cast<const short8*>(
          A + (((size_t)(mt0 + mt) * 4 + kt) * 64 + lane) * 8);
    float v[NTW][4];
#pragma unroll
    for (int i = 0; i < NTW; ++i) {
      f32x4v c = {0.f, 0.f, 0.f, 0.f};
#pragma unroll
      for (int kt = 0; kt < 4; ++kt)
        c = __builtin_amdgcn_mfma_f32_16x16x32_bf16(a[kt], bf[i][kt], c, 0, 0, 0);
      const int colL = (wv * NTW + i) * 16 + r0;
      const float bb = HASB ? bias[colL] : 0.f;
      const int rowB = (mt0 + mt) * 16 + g * 4;
#pragma unroll
      for (int q = 0; q < 4; ++q) {
        const int row = rowB + q;
        const float val = c[q] + bb;
        if (EPI == 0) {
          OutBf[(size_t)row * obstr + colL] = f2bf(val);
        } else {
          v[i][q] = val + X[(size_t)row * 128 + colL];
        }
      }
    }
    if (EPI == 4) {
      float s1[4], s2[4];
#pragma unroll
      for (int q = 0; q < 4; ++q) {
        s1[q] = v[0][q] + v[1][q];
        s2[q] = v[0][q] * v[0][q] + v[1][q] * v[1][q];
      }
#pragma unroll
      for (int o = 1; o < 16; o <<= 1)
#pragma unroll
        for (int q = 0; q < 4; ++q) { s1[q] += __shfl_xor(s1[q], o); s2[q] += __shfl_xor(s2[q], o); }
      if (r0 == 0)
#pragma unroll
        for (int q = 0; q < 4; ++q) { red[g * 4 + q][wv][0] = s1[q]; red[g * 4 + q][wv][1] = s2[q]; }
      __syncthreads();
#pragma unroll
      for (int q = 0; q < 4; ++q) {
        const int r = g * 4 + q;
        const float t1 = red[r][0][0] + red[r][1][0] + red[r][2][0] + red[r][3][0];
        const float t2 = red[r][0][1] + red[r][1][1] + red[r][2][1] + red[r][3][1];
        const float m  = t1 * (1.f / 128.f);
        const float rs = rsqrtf(t2 * (1.f / 128.f) - m * m + 1e-5f);
        const int row = (mt0 + mt) * 16 + r;
#pragma unroll
        for (int i = 0; i < 2; ++i) {
          const int col = (wv * 2 + i) * 16 + r0;
          const float o = (v[i][q] - m) * rs * gs[col] + gb[col];
          X[(size_t)row * 128 + col] = v[i][q];   // norm_first: RAW residual
          OutP[apos(row, col, 4)] = f2bf(o);      // LN'd input for next phase
        }
      }
      __syncthreads();
    }
  }
}

// fused expert FFN: H = relu(A@W1+b1) in LDS (single bf16); v = X + H@W2 + b2;
// DOLN: X = v raw, packed A = LN(v); else X = v.  512 thr, grid (NBGMAX, 2).
template<bool DOLN>
__global__ __launch_bounds__(512) void effn_kernel(
    const short* __restrict__ A, const short* __restrict__ W1b, const int strideW1,
    const float* __restrict__ b1b, const int strideB1,
    const short* __restrict__ W2b, const int strideW2,
    const float* __restrict__ b2b, const int strideB2,
    float* __restrict__ X, short* __restrict__ OutP,
    const float* __restrict__ lnsA, const float* __restrict__ lnbA, const int subOff,
    const int* __restrict__ sch)
{
  __shared__ short HsL[4 * 16 * 64 * 8];   // 64 KB, 64 rows x 512 cols bf16 packed
  __shared__ float red[16][8][2];
  const int k = (int)blockIdx.x;
  if (k >= sch[0]) return;
  const int ex  = sch[GEXP_OFF + k];
  const int mt0 = sch[GMT_OFF + k] + (int)blockIdx.y * 4;
  const short* W1p = W1b + (size_t)ex * strideW1;
  const short* W2p = W2b + (size_t)ex * strideW2;
  const float* b1 = b1b + (size_t)ex * strideB1;
  const float* b2 = b2b + (size_t)ex * strideB2;
  const float* gs = DOLN ? lnsA + ex * (NLDn * 3 * 128) + subOff : nullptr;
  const float* gb = DOLN ? lnbA + ex * (NLDn * 3 * 128) + subOff : nullptr;
  const int lane = (int)threadIdx.x & 63, wv = (int)threadIdx.x >> 6;  // 8 waves
  const int r0 = lane & 15, g = lane >> 4;
  // persistent A fragments (4 local M-tiles)
  short8 a[4][4];
#pragma unroll
  for (int mtl = 0; mtl < 4; ++mtl)
#pragma unroll
    for (int kt = 0; kt < 4; ++kt)
      a[mtl][kt] = *reinterpret_cast<const short8*>(
          A + (((size_t)(mt0 + mtl) * 4 + kt) * 64 + lane) * 8);
  // phase 1: W1 + relu -> LDS (single bf16)
#pragma unroll
  for (int i = 0; i < 4; ++i) {
    const int nt = wv * 4 + i;
    short8 bw[4];
#pragma unroll
    for (int kt = 0; kt < 4; ++kt)
      bw[kt] = *reinterpret_cast<const short8*>(
          W1p + (((size_t)(nt * 4 + kt) * 64 + lane)) * 8);
    const int col = nt * 16 + r0;
    const float bb = b1[col];
#pragma unroll
    for (int mtl = 0; mtl < 4; ++mtl) {
      f32x4v c = {0.f, 0.f, 0.f, 0.f};
#pragma unroll
      for (int kt = 0; kt < 4; ++kt)
        c = __builtin_amdgcn_mfma_f32_16x16x32_bf16(a[mtl][kt], bw[kt], c, 0, 0, 0);
#pragma unroll
      for (int q = 0; q < 4; ++q) {
        const int rl = mtl * 16 + g * 4 + q;
        HsL[hpos(rl, col)] = f2bf(fmaxf(c[q] + bb, 0.f));
      }
    }
  }
  __syncthreads();
  // phase 2: H@W2 (K=512 from LDS)
  const int col = wv * 16 + r0;
  f32x4v c2[4];
#pragma unroll
  for (int mtl = 0; mtl < 4; ++mtl) c2[mtl] = (f32x4v){0.f, 0.f, 0.f, 0.f};
#pragma unroll
  for (int kk = 0; kk < 16; ++kk) {
    const short8 bw = *reinterpret_cast<const short8*>(
        W2p + (((size_t)(wv * 16 + kk) * 64 + lane)) * 8);
#pragma unroll
    for (int mtl = 0; mtl < 4; ++mtl) {
      const short8 aw = *reinterpret_cast<const short8*>(
          HsL + (((size_t)(mtl * 16 + kk) * 64 + lane)) * 8);
      c2[mtl] = __builtin_amdgcn_mfma_f32_16x16x32_bf16(aw, bw, c2[mtl], 0, 0, 0);
    }
  }
  const float bb2 = b2[col];
  for (int mtl = 0; mtl < 4; ++mtl) {
    const int mtg = mt0 + mtl;
    float v[4];
#pragma unroll
    for (int q = 0; q < 4; ++q) {
      const int row = mtg * 16 + g * 4 + q;
      v[q] = c2[mtl][q] + bb2 + X[(size_t)row * 128 + col];
    }
    if (DOLN) {
      float s1[4], s2[4];
#pragma unroll
      for (int q = 0; q < 4; ++q) { s1[q] = v[q]; s2[q] = v[q] * v[q]; }
#pragma unroll
      for (int o = 1; o < 16; o <<= 1)
#pragma unroll
        for (int q = 0; q < 4; ++q) { s1[q] += __shfl_xor(s1[q], o); s2[q] += __shfl_xor(s2[q], o); }
      if (r0 == 0)
#pragma unroll
        for (int q = 0; q < 4; ++q) { red[g * 4 + q][wv][0] = s1[q]; red[g * 4 + q][wv][1] = s2[q]; }
      __syncthreads();
#pragma unroll
      for (int q = 0; q < 4; ++q) {
        const int r = g * 4 + q;
        float t1 = 0.f, t2 = 0.f;
#pragma unroll
        for (int w = 0; w < 8; ++w) { t1 += red[r][w][0]; t2 += red[r][w][1]; }
        const float m  = t1 * (1.f / 128.f);
        const float rs = rsqrtf(t2 * (1.f / 128.f) - m * m + 1e-5f);
        const int row = mtg * 16 + r;
        const float o = (v[q] - m) * rs * gs[col] + gb[col];
        X[(size_t)row * 128 + col] = v[q];      // norm_first: RAW residual
        OutP[apos(row, col, 4)] = f2bf(o);      // LN'd input for next layer
      }
      __syncthreads();
    } else {
#pragma unroll
      for (int q = 0; q < 4; ++q) {
        const int row = mtg * 16 + g * 4 + q;
        X[(size_t)row * 128 + col] = v[q];
      }
    }
  }
}

// per (pair, head) self-attention: QKV bf16 (stride 384) -> O packed bf16.
// grid (4096, 4), 64 threads. Wave-parallel softmax, norm folded into AV.
__global__ __launch_bounds__(64) void sattn_kernel(
    const short* __restrict__ QKVb, const int* __restrict__ prow,
    short* __restrict__ ANP)
{
  __shared__ float qs[CSn * HSTR], ks[CSn * HSTR], vs[CSn * HSTR];
  __shared__ float att[CSn * CSn];
  __shared__ float inv[CSn];
  const int i = (int)blockIdx.x, h = (int)blockIdx.y;
  const int tid = (int)threadIdx.x;
  const int row0 = prow[i];
  for (int u = tid; u < CSn * 12; u += 64) {
    const int il = u / 12, r = u % 12, which = r >> 2, d8 = r & 3;
    const short8 s = *reinterpret_cast<const short8*>(
        QKVb + (size_t)(row0 + il) * 384 + which * 128 + h * 32 + d8 * 8);
    float* dst = (which == 0 ? qs : which == 1 ? ks : vs) + il * HSTR + d8 * 8;
#pragma unroll
    for (int u8 = 0; u8 < 8; ++u8) dst[u8] = bf2f(s[u8]);
  }
  __syncthreads();
  for (int e = tid; e < CSn * CSn; e += 64) {
    const int ii = e / CSn, j = e % CSn;
    const float* qp = qs + ii * HSTR;
    const float* kp = ks + j * HSTR;
    float acc = 0.f;
#pragma unroll
    for (int d = 0; d < DHn; d += 4) {
      const float4 qa = *reinterpret_cast<const float4*>(qp + d);
      const float4 kb = *reinterpret_cast<const float4*>(kp + d);
      acc += qa.x * kb.x + qa.y * kb.y + qa.z * kb.z + qa.w * kb.w;
    }
    att[e] = acc * INV_SQRT_DH;
  }
  __syncthreads();
  if (tid < 2 * CSn) {                 // 40 lanes: 2 per row, 10 elems each
    const int r = tid >> 1, h0 = (tid & 1) * 10;
    float* row = att + r * CSn + h0;
    float m = row[0];
#pragma unroll
    for (int j = 1; j < 10; ++j) m = fmaxf(m, row[j]);
    m = fmaxf(m, __shfl_xor(m, 1));
    float s = 0.f;
#pragma unroll
    for (int j = 0; j < 10; ++j) { const float ex = expf(row[j] - m); row[j] = ex; s += ex; }
    s += __shfl_xor(s, 1);
    if ((tid & 1) == 0) inv[r] = 1.f / s;
  }
  __syncthreads();
  for (int e = tid; e < CSn * 32; e += 64) {
    const int ii = e >> 5, c = e & 31;
    const float* arow = att + ii * CSn;
    float acc = 0.f;
#pragma unroll 4
    for (int j = 0; j < CSn; ++j) acc = fmaf(arow[j], vs[j * HSTR + c], acc);
    acc *= inv[ii];
    ANP[apos(row0 + ii, h * 32 + c, 4)] = f2bf(acc);
  }
}

// per-pair cross-attention (2 keys): Qc bf16 (stride 128) + composite memkv
__global__ __launch_bounds__(256) void cattn_kernel(
    const short* __restrict__ Qb, const float* __restrict__ state,
    const float* __restrict__ C, const float* __restrict__ k0c,
    const float* __restrict__ k1c, const int layer,
    const int* __restrict__ plist, const int* __restrict__ prow,
    const int* __restrict__ pexp, short* __restrict__ ANP)
{
  __shared__ float q[CSn * Dn];
  __shared__ float memkv[2 * 256];
  __shared__ float catt[2 * Hn * CSn];
  __shared__ float st[SDn];
  const int i = (int)blockIdx.x;
  const int ex = pexp[i];
  const int b = plist[i] >> 1;
  const int li = ex * NLDn + layer;
  const int row0 = prow[i];
  const int tid = (int)threadIdx.x;

  if (tid < SDn) st[tid] = state[b * SDn + tid];
  for (int e8 = tid; e8 < CSn * 16; e8 += 256) {
    const int il = e8 >> 4, c8 = e8 & 15;
    const short8 s = *reinterpret_cast<const short8*>(
        Qb + (size_t)(row0 + il) * 128 + c8 * 8);
    float* dst = q + il * Dn + c8 * 8;
#pragma unroll
    for (int u = 0; u < 8; ++u) dst[u] = bf2f(s[u]);
  }
  __syncthreads();
  {
    const int c2 = tid;                       // 256 threads, one column each
    float acc = k0c[li * 256 + c2];
#pragma unroll
    for (int k = 0; k < SDn; ++k)
      acc = fmaf(st[k], C[((size_t)li * SDn + k) * 256 + c2], acc);
    memkv[c2] = acc;
    memkv[256 + c2] = k1c[li * 256 + c2];
  }
  __syncthreads();
  for (int e = tid; e < Hn * CSn; e += 256) {
    const int h = e / CSn, il = e % CSn;
    const float* qp = q + il * Dn + h * DHn;
    float s0 = 0.f, s1 = 0.f;
#pragma unroll
    for (int d = 0; d < DHn; d += 4) {
      const float4 q4 = *reinterpret_cast<const float4*>(qp + d);
      const float4 k0 = *reinterpret_cast<const float4*>(memkv + 0 * 256 + h * DHn + d);
      const float4 k1 = *reinterpret_cast<const float4*>(memkv + 1 * 256 + h * DHn + d);
      s0 += q4.x * k0.x + q4.y * k0.y + q4.z * k0.z + q4.w * k0.w;
      s1 += q4.x * k1.x + q4.y * k1.y + q4.z * k1.z + q4.w * k1.w;
    }
    s0 *= INV_SQRT_DH; s1 *= INV_SQRT_DH;
    const float m = fmaxf(s0, s1);
    const float e0 = expf(s0 - m), e1 = expf(s1 - m);
    const float inv = 1.f / (e0 + e1);
    catt[e * 2] = e0 * inv; catt[e * 2 + 1] = e1 * inv;
  }
  __syncthreads();
  for (int e = tid; e < CSn * Dn; e += 256) {
    const int il = e >> 7, c = e & 127, h = c >> 5;
    const int a = (h * CSn + il) * 2;
    const float v = catt[a]     * memkv[0 * 256 + Dn + c]
                  + catt[a + 1] * memkv[1 * 256 + Dn + c];
    ANP[apos(row0 + il, c, 4)] = f2bf(v);
  }
}

__global__ __launch_bounds__(256) void head_kernel(
    const float* __restrict__ X, const int* __restrict__ plist,
    const int* __restrict__ prow, const int* __restrict__ pexp,
    const float* __restrict__ rwgt, const float* __restrict__ hW,
    const float* __restrict__ hb, float* __restrict__ Rbuf)
{
  __shared__ float xr[CSn * Dn];
  const int i = (int)blockIdx.x;
  const int ex = pexp[i];
  const int orig = plist[i];
  const int row0 = prow[i];
  const float wgt = rwgt[orig];
  for (int e4 = (int)threadIdx.x; e4 < CSn * 32; e4 += 256) {
    const int il = e4 >> 5, c4 = (e4 & 31) * 4;
    *reinterpret_cast<float4*>(xr + il * Dn + c4) =
        *reinterpret_cast<const float4*>(X + (size_t)(row0 + il) * 128 + c4);
  }
  __syncthreads();
  const int e = (int)threadIdx.x;
  if (e < CSn * JDn) {
    const int t = e / JDn, j = e - t * JDn;
    const float* w = hW + ex * Dn * JDn + j;
    float acc = hb[ex * JDn + j];
#pragma unroll 4
    for (int kk = 0; kk < Dn; ++kk) acc = fmaf(xr[t * Dn + kk], w[kk * JDn], acc);
    Rbuf[(size_t)i * 140 + e] = wgt * acc;
  }
}

__global__ void combine_kernel(const float* __restrict__ Rbuf,
                               const int* __restrict__ ppos, float* __restrict__ out)
{
  const int idx = (int)blockIdx.x * 256 + (int)threadIdx.x;
  if (idx >= Bn * 140) return;
  const int b = idx / 140, e = idx - b * 140;
  out[idx] = Rbuf[(size_t)ppos[2 * b] * 140 + e] + Rbuf[(size_t)ppos[2 * b + 1] * 140 + e];
}

// ---------------------------------------------------------------------------
__global__ void qpe_kernel(float* qpe)
{
  const int e = (int)blockIdx.x * 256 + (int)threadIdx.x;
  if (e < CSn * Dn) {
    const int t = e >> 7, d = e & 127;
    const float j  = (float)(d & ~1);
    const float dv = expf(j * (-logf(10000.f) / 128.f));
    const float a  = (float)t * dv;
    qpe[e] = (d & 1) ? cosf(a) : sinf(a);
  }
}

} // namespace

// ---------------------------------------------------------------------------
extern "C" void kernel_launch(void* const* d_in, const int* in_sizes, int n_in,
                              void* d_out, int out_size, void* d_ws, size_t ws_size,
                              hipStream_t stream)
{
  (void)in_sizes; (void)n_in; (void)out_size;

  const int*   ids     = (const int*)  d_in[0];
  const float* state   = (const float*)d_in[1];
  const float* tok_emb = (const float*)d_in[2];
  const float* pos_emb = (const float*)d_in[3];

  // persistent workspace (256B-aligned cursor)
  char* cur = (char*)d_ws;
  auto alloc = [&cur](size_t bytes) -> char* {
    char* p = cur; cur += (bytes + 255) & ~(size_t)255; return p;
  };
  float* qpe    = (float*)alloc(4096 * 4);
  float* intent = (float*)alloc((size_t)Bn * Dn * 4);
  int*   ridx   = (int*)  alloc(PAIRS * 4);
  float* rwgt   = (float*)alloc(PAIRS * 4);
  short* pQ     = (short*)alloc((size_t)36 * 49152 * 2);   // expert packs (single bf16)
  short* pO     = (short*)alloc((size_t)36 * 16384 * 2);
  short* pF1    = (short*)alloc((size_t)18 * 65536 * 2);
  short* pF2    = (short*)alloc((size_t)18 * 65536 * 2);
  short* pbQ    = (short*)alloc((size_t)4 * 98304 * 2);    // BERT packs (split hi/lo)
  short* pbO    = (short*)alloc((size_t)4 * 32768 * 2);
  short* pbW1   = (short*)alloc((size_t)4 * 131072 * 2);
  short* pbW2   = (short*)alloc((size_t)4 * 131072 * 2);
  int*   sch    = (int*)  alloc(2048 * 4);
  int*   plist  = (int*)  alloc(PAIRS * 4);
  int*   prow   = (int*)  alloc(PAIRS * 4);
  int*   pexp   = (int*)  alloc(PAIRS * 4);
  int*   ppos   = (int*)  alloc(PAIRS * 4);
  float* Cmat   = (float*)alloc((size_t)18 * SDn * 256 * 4);  // 294912 B
  float* k0c    = (float*)alloc((size_t)18 * 256 * 4);
  float* k1c    = (float*)alloc((size_t)18 * 256 * 4);
  constexpr size_t ARENA_BYTES = 192806912;
  char* arena = alloc(ARENA_BYTES);
  if ((size_t)(cur - (char*)d_ws) > ws_size) return;  // ws confirmed sufficient R4-R14

  // BERT views
  float* Xb  = (float*)(arena);                          // 25.2 MB
  short* Ah  = (short*)(arena + 25165824);               // 12.6 MB
  short* Al  = (short*)(arena + 37748736);               // 12.6 MB
  float* SBb = (float*)(arena + 50331648);               // QKV fp32 75.5 MB
  // expert views
  float* X2   = (float*)(arena);                         // 42.3 MB
  short* ANP  = (short*)(arena + 42336256);              // 21.2 MB
  short* SBh  = (short*)(arena + 63504384);              // bf16 QKV/Qc
  float* Rbuf = (float*)(arena + 190513152);             // 2.3 MB

  qpe_kernel<<<dim3(10), dim3(256), 0, stream>>>(qpe);

  // ---- weight packing + composite cross-attn factors
  {
    const int tq = 36 * 6144;
    pack_kernel<<<dim3((tq + 255) / 256), dim3(256), 0, stream>>>(
        (const float*)d_in[34], pQ, 128, 384, tq);
    const int to = 36 * 2048;
    pack_kernel<<<dim3((to + 255) / 256), dim3(256), 0, stream>>>(
        (const float*)d_in[36], pO, 128, 128, to);
    const int t1c = 18 * 8192;
    pack_kernel<<<dim3((t1c + 255) / 256), dim3(256), 0, stream>>>(
        (const float*)d_in[40], pF1, 128, 512, t1c);
    const int t2c = 18 * 8192;
    pack_kernel<<<dim3((t2c + 255) / 256), dim3(256), 0, stream>>>(
        (const float*)d_in[42], pF2, 512, 128, t2c);
    const int bq = 4 * 6144;
    pack2_kernel<<<dim3((bq + 255) / 256), dim3(256), 0, stream>>>(
        (const float*)d_in[4], pbQ, 128, 384, bq);
    const int bo = 4 * 2048;
    pack2_kernel<<<dim3((bo + 255) / 256), dim3(256), 0, stream>>>(
        (const float*)d_in[6], pbO, 128, 128, bo);
    const int bw1 = 4 * 8192;
    pack2_kernel<<<dim3((bw1 + 255) / 256), dim3(256), 0, stream>>>(
        (const float*)d_in[8], pbW1, 128, 512, bw1);
    const int bw2 = 4 * 8192;
    pack2_kernel<<<dim3((bw2 + 255) / 256), dim3(256), 0, stream>>>(
        (const float*)d_in[10], pbW2, 512, 128, bw2);
    compose_kernel<<<dim3(En * NLDn), dim3(256), 0, stream>>>(
        (const float*)d_in[30], (const float*)d_in[31], (const float*)d_in[33],
        (const float*)d_in[34], (const float*)d_in[35], Cmat, k0c, k1c);
  }

  // ---- BERT phase pipeline (fused FFN)
  {
    const float* bq  = (const float*)d_in[5];
    const float* bo  = (const float*)d_in[7];
    const float* b1  = (const float*)d_in[9];
    const float* b2  = (const float*)d_in[11];
    const float* lns = (const float*)d_in[12];
    const float* lnb = (const float*)d_in[13];

    bembed_kernel<<<dim3(ROWSB / 16), dim3(256), 0, stream>>>(
        ids, tok_emb, pos_emb, Xb, Ah, Al);
    for (int l = 0; l < NLBn; ++l) {
      bqkv_kernel<<<dim3(ROWSB / 64, 3), dim3(256), 0, stream>>>(
          Ah, Al, pbQ + (size_t)l * 98304, bq + l * 384, SBb);
      battn_kernel<<<dim3(Bn, Hn), dim3(64), 0, stream>>>(SBb, ids, Ah, Al);
      bo_ln_kernel<<<dim3(ROWSB / 64), dim3(256), 0, stream>>>(
          Ah, Al, pbO + (size_t)l * 32768, bo + l * 128,
          lns + l * 256, lnb + l * 256, Xb, Ah, Al);
      bffn_kernel<<<dim3(ROWSB / 32), dim3(512), 0, stream>>>(
          Ah, Al, pbW1 + (size_t)l * 131072, pbW2 + (size_t)l * 131072,
          b1 + l * 512, b2 + l * 128,
          lns + l * 256 + 128, lnb + l * 256 + 128, Xb, Ah, Al);
    }
    bintent_kernel<<<dim3(Bn / 4), dim3(256), 0, stream>>>(
        Xb, (const float*)d_in[14], (const float*)d_in[15], intent);
  }

  // ---- router
  {
    RouterP rp;
    rp.state = state; rp.intent = intent;
    rp.se_W1 = (const float*)d_in[16]; rp.se_b1 = (const float*)d_in[17];
    rp.se_W2 = (const float*)d_in[18]; rp.se_b2 = (const float*)d_in[19];
    rp.se_ln_s = (const float*)d_in[20]; rp.se_ln_b = (const float*)d_in[21];
    rp.r_W1 = (const float*)d_in[22]; rp.r_b1 = (const float*)d_in[23];
    rp.r_W2 = (const float*)d_in[24]; rp.r_b2 = (const float*)d_in[25];
    rp.r_ln_s = (const float*)d_in[26]; rp.r_ln_b = (const float*)d_in[27];
    rp.gate_W = (const float*)d_in[28]; rp.gate_b = (const float*)d_in[29];
    rp.ridx = ridx; rp.rwgt = rwgt;
    router_kernel<<<dim3(Bn), dim3(128), 0, stream>>>(rp);
  }

  const float* ab   = (const float*)d_in[35];
  const float* abo  = (const float*)d_in[37];
  const float* lnsA = (const float*)d_in[38];
  const float* lnbA = (const float*)d_in[39];
  const float* fb1A = (const float*)d_in[41];
  const float* fb2A = (const float*)d_in[43];
  const float* hW   = (const float*)d_in[44];
  const float* hB   = (const float*)d_in[45];

  // ---- expert phase pipeline (fused FFN; grouped GEMMs M-split gridDim.y=2)
  {
    sched_kernel<<<dim3(1), dim3(256), 0, stream>>>(ridx, sch, plist, prow, pexp, ppos);
    xinit_kernel<<<dim3(MPMAX * 32 / 256), dim3(256), 0, stream>>>(qpe, sch, X2);
    ln_pack_kernel<<<dim3(MPMAX / 16), dim3(256), 0, stream>>>(
        X2, ANP, lnsA, lnbA, 0, sch);
    for (int l = 0; l < NLDn; ++l) {
      // self-attention block
      gemm_k128<6, 0, true><<<dim3(NBGMAX, 2), dim3(256), 0, stream>>>(
          ANP, pQ + (l * 2 + 0) * 49152, 294912,
          ab + (l * 2 + 0) * 384, 2304, 0,
          SBh, 384, nullptr, nullptr, nullptr, 0, nullptr, sch);
      sattn_kernel<<<dim3(PAIRS, Hn), dim3(64), 0, stream>>>(SBh, prow, ANP);
      gemm_k128<2, 4, true><<<dim3(NBGMAX, 2), dim3(256), 0, stream>>>(
          ANP, pO + (l * 2 + 0) * 16384, 98304,
          abo + (l * 2 + 0) * 128, 768, 0,
          nullptr, 0, ANP, lnsA, lnbA, (l * 3 + 1) * 128, X2, sch);
      // cross-attention block
      gemm_k128<2, 0, true><<<dim3(NBGMAX, 2), dim3(256), 0, stream>>>(
          ANP, pQ + (l * 2 + 1) * 49152, 294912,
          ab + (l * 2 + 1) * 384, 2304, 0,
          SBh, 128, nullptr, nullptr, nullptr, 0, nullptr, sch);
      cattn_kernel<<<dim3(PAIRS), dim3(256), 0, stream>>>(
          SBh, state, Cmat, k0c, k1c, l, plist, prow, pexp, ANP);
      gemm_k128<2, 4, true><<<dim3(NBGMAX, 2), dim3(256), 0, stream>>>(
          ANP, pO + (l * 2 + 1) * 16384, 98304,
          abo + (l * 2 + 1) * 128, 768, 0,
          nullptr, 0, ANP, lnsA, lnbA, (l * 3 + 2) * 128, X2, sch);
      // fused FFN (W1 + relu + W2 in one kernel, H in LDS)
      if (l < NLDn - 1) {
        effn_kernel<true><<<dim3(NBGMAX, 2), dim3(512), 0, stream>>>(
            ANP, pF1 + l * 65536, 196608, fb1A + l * 512, 1536,
            pF2 + l * 65536, 196608, fb2A + l * 128, 384,
            X2, ANP, lnsA, lnbA, ((l + 1) * 3 + 0) * 128, sch);
      } else {
        effn_kernel<false><<<dim3(NBGMAX, 2), dim3(512), 0, stream>>>(
            ANP, pF1 + l * 65536, 196608, fb1A + l * 512, 1536,
            pF2 + l * 65536, 196608, fb2A + l * 128, 384,
            X2, nullptr, nullptr, nullptr, 0, sch);
      }
    }
    head_kernel<<<dim3(PAIRS), dim3(256), 0, stream>>>(
        X2, plist, prow, pexp, rwgt, hW, hB, Rbuf);
    combine_kernel<<<dim3((Bn * 140 + 255) / 256), dim3(256), 0, stream>>>(
        Rbuf, ppos, (float*)d_out);
  }
}